// Round 9
// baseline (197.178 us; speedup 1.0000x reference)
//
#include <hip/hip_runtime.h>
#include <hip/hip_bf16.h>
#include <math.h>

#define B_ 64
#define S_ 512
#define D_ 1024
#define H_ 512
#define WSEG 96
#define TSEG 24
#define CSEG 128
#define NSEG (WSEG + TSEG + CSEG) /* 248 */
#define ESEG (TSEG + CSEG + 1)    /* 153 */
#define EPAD 160                  /* ent rows padded per batch */

typedef __bf16 bf16x8 __attribute__((ext_vector_type(8)));
typedef __bf16 bf16x4 __attribute__((ext_vector_type(4)));
typedef float f32x4 __attribute__((ext_vector_type(4)));

#define GL16(g, l)                                                      \
  __builtin_amdgcn_global_load_lds(                                     \
      (const __attribute__((address_space(1))) void*)(g),               \
      (__attribute__((address_space(3))) void*)(l), 16, 0, 0)

__device__ inline float tanh_fast(float x) {
  const float xc = fminf(12.f, fmaxf(-12.f, x));
  const float e = __expf(2.f * xc);
  return (e - 1.f) * __builtin_amdgcn_rcpf(e + 1.f);
}

// ---------------------------------------------------------------------------
// Stage 1a: build CSR token lists per (b, segtype, seg). One block per b.
// ---------------------------------------------------------------------------
__global__ __launch_bounds__(512) void build_csr_kernel(
    const int* __restrict__ wseg, const int* __restrict__ tseg,
    const int* __restrict__ cseg, int* __restrict__ lw, int* __restrict__ lt,
    int* __restrict__ lc, int* __restrict__ meta) {
  __shared__ int wid[S_], tid_[S_], cid[S_];
  __shared__ int cw[WSEG], ct[TSEG], cc[CSEG];
  const int t = threadIdx.x;
  const int b = blockIdx.x;

  const int myw = wseg[b * S_ + t];
  const int myt = tseg[b * S_ + t];
  const int myc = cseg[b * S_ + t];
  wid[t] = myw;
  tid_[t] = myt;
  cid[t] = myc;
  if (t < WSEG) cw[t] = 0;
  if (t < TSEG) ct[t] = 0;
  if (t < CSEG) cc[t] = 0;
  __syncthreads();

  atomicAdd(&cw[myw], 1);
  atomicAdd(&ct[myt], 1);
  atomicAdd(&cc[myc], 1);
  __syncthreads();

  if (t == 0) {
    int r = 0;
    for (int i = 0; i < WSEG; ++i) {
      const int c = cw[i];
      meta[b * NSEG + i] = r | (c << 16);
      cw[i] = r;
      r += c;
    }
    r = 0;
    for (int i = 0; i < TSEG; ++i) {
      const int c = ct[i];
      meta[b * NSEG + WSEG + i] = r | (c << 16);
      ct[i] = r;
      r += c;
    }
    r = 0;
    for (int i = 0; i < CSEG; ++i) {
      const int c = cc[i];
      meta[b * NSEG + WSEG + TSEG + i] = r | (c << 16);
      cc[i] = r;
      r += c;
    }
  }
  __syncthreads();

  int rw = 0, rt = 0, rc = 0;
  for (int s = 0; s < S_; ++s) {
    const int below = (s < t) ? 1 : 0;
    rw += below & (wid[s] == myw);
    rt += below & (tid_[s] == myt);
    rc += below & (cid[s] == myc);
  }
  lw[b * S_ + cw[myw] + rw] = t;
  lt[b * S_ + ct[myt] + rt] = t;
  lc[b * S_ + cc[myc] + rc] = t;
}

// ---------------------------------------------------------------------------
// Stage 1b: ONE-PASS gather v2. Grid (32 d-slices, B), 256 thr, ~71 KB LDS
// (2 blocks/CU). q[b,:,d0:d0+32] staged once (q read ONCE from HBM total);
// token lists + meta staged in LDS (broadcast reads). Thread (col = t&31,
// rowgroup = t>>5) accumulates its rows' token sums with a 4-deep unroll:
// 4 INDEPENDENT qs reads per sl-quad -> no serial LDS latency chain (the
// R5 one-pass failure mode). Carried dep = 4cy adds only.
// ---------------------------------------------------------------------------
__global__ __launch_bounds__(256) void gather2_kernel(
    const float* __restrict__ q, const int* __restrict__ lw,
    const int* __restrict__ lt, const int* __restrict__ lc,
    const int* __restrict__ meta, __bf16* __restrict__ Ah,
    __bf16* __restrict__ Al) {
  __shared__ float qs[S_][32];  // 64 KB
  __shared__ int sl[3 * S_];    // 6 KB
  __shared__ int smeta[NSEG];   // 1 KB
  const int t = threadIdx.x;
  const int d0 = blockIdx.x * 32;
  const int b = blockIdx.y;

  const float* qb = q + (size_t)b * S_ * D_ + d0;
  {
    const int s0 = t >> 3, g = (t & 7) << 2;
#pragma unroll
    for (int it = 0; it < 16; ++it) {
      const int s = s0 + it * 32;
      *(float4*)&qs[s][g] = *(const float4*)(qb + (size_t)s * D_ + g);
    }
  }
  {
    const int base = b * S_;
#pragma unroll
    for (int it = 0; it < 2; ++it) {
      const int i = t + it * 256;
      sl[i] = lw[base + i];
      sl[S_ + i] = lt[base + i];
      sl[2 * S_ + i] = lc[base + i];
    }
    if (t < NSEG) smeta[t] = meta[b * NSEG + t];
  }
  __syncthreads();

  const int col = t & 31;
  const int rg = t >> 5;  // 0..7

  for (int r = rg; r < NSEG; r += 8) {
    const int m = smeta[r];
    const int start = m & 0xFFFF, count = m >> 16;
    const int* lp;
    int arow;
    if (r < WSEG) {
      lp = sl;
      arow = b * WSEG + r;
    } else if (r < WSEG + TSEG) {
      lp = sl + S_;
      arow = B_ * WSEG + b * TSEG + (r - WSEG);
    } else {
      lp = sl + 2 * S_;
      arow = B_ * (WSEG + TSEG) + b * CSEG + (r - WSEG - TSEG);
    }
    lp += start;
    float acc = 0.f;
    int i = 0;
    for (; i + 4 <= count; i += 4) {
      const int s0 = lp[i], s1 = lp[i + 1], s2 = lp[i + 2], s3 = lp[i + 3];
      acc += qs[s0][col] + qs[s1][col] + qs[s2][col] + qs[s3][col];
    }
    for (; i < count; ++i) acc += qs[lp[i]][col];
    const __bf16 h = (__bf16)acc;
    Ah[(size_t)arow * D_ + d0 + col] = h;
    Al[(size_t)arow * D_ + d0 + col] = (__bf16)(acc - (float)h);
  }
}

// ---------------------------------------------------------------------------
// Stage 1c: transpose weights -> Wt hi/lo bf16 [3][512][1024].
// ---------------------------------------------------------------------------
__global__ __launch_bounds__(256) void prep_w_kernel(
    const float* __restrict__ Ws, const float* __restrict__ Wt_,
    const float* __restrict__ Wc, __bf16* __restrict__ Wth,
    __bf16* __restrict__ Wtl) {
  __shared__ float tile[64][65];
  const int z = blockIdx.z;
  const float* W = (z == 0) ? Ws : ((z == 1) ? Wt_ : Wc);
  const int k0 = blockIdx.y * 64, n0 = blockIdx.x * 64;
  const int tx = threadIdx.x & 63, ty = threadIdx.x >> 6;

#pragma unroll
  for (int i = 0; i < 16; ++i) {
    const int kl = i * 4 + ty;
    tile[kl][tx] = W[(size_t)(k0 + kl) * H_ + n0 + tx];
  }
  __syncthreads();
  __bf16* oh = Wth + (size_t)z * H_ * D_;
  __bf16* ol = Wtl + (size_t)z * H_ * D_;
#pragma unroll
  for (int i = 0; i < 16; ++i) {
    const int nl = i * 4 + ty;
    const float v = tile[tx][nl];
    const __bf16 h = (__bf16)v;
    oh[(size_t)(n0 + nl) * D_ + k0 + tx] = h;
    ol[(size_t)(n0 + nl) * D_ + k0 + tx] = (__bf16)(v - (float)h);
  }
}

// ---------------------------------------------------------------------------
// Stage 2: split-bf16 MFMA GEMM, 128x128 tile, BK=64, tanh epilogue.
// (R6-proven version: single-buffered, GL16 staging, XOR-swizzled reads.)
// ---------------------------------------------------------------------------
__global__ __launch_bounds__(256) void gemm3_kernel(
    const __bf16* __restrict__ Ah, const __bf16* __restrict__ Al,
    const __bf16* __restrict__ Wth, const __bf16* __restrict__ Wtl,
    __bf16* __restrict__ sub_h, __bf16* __restrict__ sub_l,
    __bf16* __restrict__ ent_h, __bf16* __restrict__ ent_l, int m_offset) {
  __shared__ __align__(16) char smem[65536];
  char* sAh = smem;
  char* sAl = smem + 16384;
  char* sBh = smem + 32768;
  char* sBl = smem + 49152;

  const int tid = threadIdx.x;
  const int wid = tid >> 6;
  const int lane = tid & 63;
  const int m0 = m_offset + blockIdx.y * 128;
  const int n0 = blockIdx.x * 128;
  const int id = (m0 < B_ * WSEG) ? 0 : ((m0 < B_ * (WSEG + TSEG)) ? 1 : 2);

  const __bf16* Bh_g = Wth + (size_t)id * H_ * D_ + (size_t)n0 * D_;
  const __bf16* Bl_g = Wtl + (size_t)id * H_ * D_ + (size_t)n0 * D_;
  const __bf16* Ah_g = Ah + (size_t)m0 * D_;
  const __bf16* Al_g = Al + (size_t)m0 * D_;

  const int rsub = lane >> 3;
  const int csrc = (lane & 7) ^ rsub;

  const int wr = wid >> 1, wc = wid & 1;
  const int arow0 = wr * 64 + (lane & 15);
  const int brow0 = wc * 64 + (lane & 15);
  const int cbase = (lane >> 4) * 16;
  const int sw = (lane & 7) << 4;

  f32x4 acc[4][4] = {};

#pragma unroll 1
  for (int kt = 0; kt < D_ / 64; ++kt) {
    __syncthreads();
    const size_t kofs = (size_t)kt * 64 + (size_t)csrc * 8;
#pragma unroll
    for (int j = 0; j < 4; ++j) {
      const int i = wid * 4 + j;
      const size_t grow = (size_t)(i * 8 + rsub) * D_ + kofs;
      GL16(Ah_g + grow, sAh + i * 1024);
      GL16(Al_g + grow, sAl + i * 1024);
      GL16(Bh_g + grow, sBh + i * 1024);
      GL16(Bl_g + grow, sBl + i * 1024);
    }
    __syncthreads();

#pragma unroll
    for (int ks = 0; ks < 2; ++ks) {
      const int cc = ((cbase + ks * 64) ^ sw);
      bf16x8 ah[4], al_[4], bh[4], bl_[4];
#pragma unroll
      for (int mi = 0; mi < 4; ++mi) {
        const int off = (arow0 + mi * 16) * 128 + cc;
        ah[mi] = *(const bf16x8*)(sAh + off);
        al_[mi] = *(const bf16x8*)(sAl + off);
      }
#pragma unroll
      for (int ni = 0; ni < 4; ++ni) {
        const int off = (brow0 + ni * 16) * 128 + cc;
        bh[ni] = *(const bf16x8*)(sBh + off);
        bl_[ni] = *(const bf16x8*)(sBl + off);
      }
#pragma unroll
      for (int mi = 0; mi < 4; ++mi)
#pragma unroll
        for (int ni = 0; ni < 4; ++ni) {
          acc[mi][ni] = __builtin_amdgcn_mfma_f32_16x16x32_bf16(
              ah[mi], bh[ni], acc[mi][ni], 0, 0, 0);
          acc[mi][ni] = __builtin_amdgcn_mfma_f32_16x16x32_bf16(
              ah[mi], bl_[ni], acc[mi][ni], 0, 0, 0);
          acc[mi][ni] = __builtin_amdgcn_mfma_f32_16x16x32_bf16(
              al_[mi], bh[ni], acc[mi][ni], 0, 0, 0);
        }
    }
  }

  const int rowb = m0 + wr * 64 + (lane >> 4) * 4;
  const int colb = n0 + wc * 64 + (lane & 15);
#pragma unroll
  for (int mi = 0; mi < 4; ++mi)
#pragma unroll
    for (int ni = 0; ni < 4; ++ni) {
      const f32x4 v = acc[mi][ni];
      const int col = colb + ni * 16;
#pragma unroll
      for (int r = 0; r < 4; ++r) {
        const int row = rowb + mi * 16 + r;
        const float val = tanh_fast(v[r]);
        const __bf16 h = (__bf16)val;
        const __bf16 l = (__bf16)(val - (float)h);
        size_t oix;
        __bf16 *oh, *ol;
        if (id == 0) {
          oix = (size_t)row * H_ + col;
          oh = sub_h;
          ol = sub_l;
        } else if (id == 1) {
          const int lr = row - B_ * WSEG;
          const int bb = lr / TSEG;
          const int rr = lr - bb * TSEG;
          oix = ((size_t)bb * EPAD + rr) * H_ + col;
          oh = ent_h;
          ol = ent_l;
        } else {
          const int lr = row - B_ * (WSEG + TSEG);
          const int bb = lr >> 7;
          const int rr = lr & 127;
          oix = ((size_t)bb * EPAD + TSEG + rr) * H_ + col;
          oh = ent_h;
          ol = ent_l;
        }
        oh[oix] = h;
        ol[oix] = l;
      }
    }
}

// Stage 2b: ent row 152 = no_entry (hi/lo, raw); rows 153..159 zeroed.
__global__ __launch_bounds__(512) void ne_fill_kernel(
    const float* __restrict__ ne, __bf16* __restrict__ ent_h,
    __bf16* __restrict__ ent_l) {
  const int h = threadIdx.x;
  const int b = blockIdx.x;
  const float v = ne[h];
  const __bf16 hi = (__bf16)v;
  const __bf16 lo = (__bf16)(v - (float)hi);
  ent_h[((size_t)b * EPAD + 152) * H_ + h] = hi;
  ent_l[((size_t)b * EPAD + 152) * H_ + h] = lo;
#pragma unroll
  for (int r = 153; r < EPAD; ++r) {
    ent_h[((size_t)b * EPAD + r) * H_ + h] = (__bf16)0.f;
    ent_l[((size_t)b * EPAD + r) * H_ + h] = (__bf16)0.f;
  }
}

// ---------------------------------------------------------------------------
// Stage 3: att = softmax(sub @ ent^T) via split-bf16 MFMA.
// Grid = B*2 (2 blocks/batch, 48 rows each), 192 thr (3 waves).
// ---------------------------------------------------------------------------
__global__ __launch_bounds__(192) void attn_mfma_kernel(
    const __bf16* __restrict__ sub_h, const __bf16* __restrict__ sub_l,
    const __bf16* __restrict__ ent_h, const __bf16* __restrict__ ent_l,
    float* __restrict__ out) {
  __shared__ __align__(16) char smem[53248];
  char* sSh = smem;           // [48][64] bf16: 6 KB
  char* sSl = smem + 6144;    // 6 KB
  char* sEh = smem + 12288;   // [160][64] bf16: 20 KB
  char* sEl = smem + 32768;   // 20 KB

  const int tid = threadIdx.x;
  const int wid = tid >> 6;
  const int lane = tid & 63;
  const int b = blockIdx.x >> 1;
  const int half = blockIdx.x & 1;

  const __bf16* Sh_g = sub_h + ((size_t)b * WSEG + half * 48) * H_;
  const __bf16* Sl_g = sub_l + ((size_t)b * WSEG + half * 48) * H_;
  const __bf16* Eh_g = ent_h + (size_t)b * EPAD * H_;
  const __bf16* El_g = ent_l + (size_t)b * EPAD * H_;

  const int rsub = lane >> 3;
  const int csrc = (lane & 7) ^ rsub;

  const int arow0 = wid * 16 + (lane & 15);
  const int brow0 = lane & 15;
  const int cbase = (lane >> 4) * 16;
  const int sw = (lane & 7) << 4;

  f32x4 acc[10] = {};

#pragma unroll 1
  for (int kt = 0; kt < H_ / 64; ++kt) {
    __syncthreads();
    const size_t kofs = (size_t)kt * 64 + (size_t)csrc * 8;
#pragma unroll
    for (int j = 0; j < 18; ++j) {
      const int ig = wid * 18 + j;
      if (ig < 6) {
        GL16(Sh_g + (size_t)(ig * 8 + rsub) * H_ + kofs, sSh + ig * 1024);
      } else if (ig < 12) {
        const int i = ig - 6;
        GL16(Sl_g + (size_t)(i * 8 + rsub) * H_ + kofs, sSl + i * 1024);
      } else if (ig < 32) {
        const int i = ig - 12;
        GL16(Eh_g + (size_t)(i * 8 + rsub) * H_ + kofs, sEh + i * 1024);
      } else if (ig < 52) {
        const int i = ig - 32;
        GL16(El_g + (size_t)(i * 8 + rsub) * H_ + kofs, sEl + i * 1024);
      }
    }
    __syncthreads();

#pragma unroll
    for (int ks = 0; ks < 2; ++ks) {
      const int cc = ((cbase + ks * 64) ^ sw);
      const int aoff = arow0 * 128 + cc;
      const bf16x8 ah = *(const bf16x8*)(sSh + aoff);
      const bf16x8 al_ = *(const bf16x8*)(sSl + aoff);
#pragma unroll
      for (int ni = 0; ni < 10; ++ni) {
        const int off = (brow0 + ni * 16) * 128 + cc;
        const bf16x8 bh = *(const bf16x8*)(sEh + off);
        const bf16x8 bl_ = *(const bf16x8*)(sEl + off);
        acc[ni] = __builtin_amdgcn_mfma_f32_16x16x32_bf16(ah, bh, acc[ni], 0,
                                                          0, 0);
        acc[ni] = __builtin_amdgcn_mfma_f32_16x16x32_bf16(ah, bl_, acc[ni], 0,
                                                          0, 0);
        acc[ni] = __builtin_amdgcn_mfma_f32_16x16x32_bf16(al_, bh, acc[ni], 0,
                                                          0, 0);
      }
    }
  }

  __syncthreads();
  float (*lg)[EPAD] = (float(*)[EPAD])smem;  // 48*160*4 = 30720 B
  const int rowb = wid * 16 + (lane >> 4) * 4;
  const int colb = lane & 15;
#pragma unroll
  for (int ni = 0; ni < 10; ++ni) {
    const f32x4 v = acc[ni];
#pragma unroll
    for (int r = 0; r < 4; ++r) lg[rowb + r][colb + ni * 16] = v[r];
  }
  __syncthreads();

  for (int r = wid; r < 48; r += 3) {
    const float x0 = lg[r][lane];
    const float x1 = lg[r][lane + 64];
    const bool has2 = (lane + 128) < ESEG;
    const float x2 = has2 ? lg[r][lane + 128] : -INFINITY;
    float m = fmaxf(fmaxf(x0, x1), x2);
#pragma unroll
    for (int off = 32; off >= 1; off >>= 1) m = fmaxf(m, __shfl_xor(m, off, 64));
    const float p0 = expf(x0 - m);
    const float p1 = expf(x1 - m);
    const float p2 = has2 ? expf(x2 - m) : 0.f;
    float ssum = p0 + p1 + p2;
#pragma unroll
    for (int off = 32; off >= 1; off >>= 1) ssum += __shfl_xor(ssum, off, 64);
    const float inv = 1.f / ssum;
    float* ob = out + ((size_t)(b * WSEG + half * 48 + r)) * ESEG;
    ob[lane] = p0 * inv;
    ob[lane + 64] = p1 * inv;
    if (has2) ob[lane + 128] = p2 * inv;
  }
}

// ---------------------------------------------------------------------------
extern "C" void kernel_launch(void* const* d_in, const int* in_sizes, int n_in,
                              void* d_out, int out_size, void* d_ws,
                              size_t ws_size, hipStream_t stream) {
  const float* q = (const float*)d_in[0];
  const float* Wsub = (const float*)d_in[1];
  const float* Wtab = (const float*)d_in[2];
  const float* Wcol = (const float*)d_in[3];
  const float* ne = (const float*)d_in[4];
  const int* wseg = (const int*)d_in[5];
  const int* tseg = (const int*)d_in[6];
  const int* cseg = (const int*)d_in[7];
  float* out = (float*)d_out;

  // flat workspace layout (~105MB of the ~512MB ws)
  char* w = (char*)d_ws;
  __bf16* Ah = (__bf16*)(w);                 // 32,505,856
  __bf16* Al = (__bf16*)(w + 32505856);      // 32,505,856
  __bf16* ent_h = (__bf16*)(w + 65011712);   // 10,485,760
  __bf16* ent_l = (__bf16*)(w + 75497472);   // 10,485,760
  __bf16* Wth = (__bf16*)(w + 85983232);     //  3,145,728
  __bf16* Wtl = (__bf16*)(w + 89128960);     //  3,145,728
  __bf16* sub_h = (__bf16*)(w + 92274688);   //  6,291,456
  __bf16* sub_l = (__bf16*)(w + 98566144);   //  6,291,456
  int* lw = (int*)(w + 104857600);
  int* lt = (int*)(w + 104988672);
  int* lc = (int*)(w + 105119744);
  int* meta = (int*)(w + 105250816);

  build_csr_kernel<<<B_, 512, 0, stream>>>(wseg, tseg, cseg, lw, lt, lc, meta);
  gather2_kernel<<<dim3(32, B_), 256, 0, stream>>>(q, lw, lt, lc, meta, Ah,
                                                   Al);
  prep_w_kernel<<<dim3(8, 16, 3), 256, 0, stream>>>(Wsub, Wtab, Wcol, Wth,
                                                    Wtl);
  gemm3_kernel<<<dim3(4, 124), 256, 0, stream>>>(Ah, Al, Wth, Wtl, sub_h,
                                                 sub_l, ent_h, ent_l, 0);
  ne_fill_kernel<<<B_, 512, 0, stream>>>(ne, ent_h, ent_l);
  attn_mfma_kernel<<<B_ * 2, 192, 0, stream>>>(sub_h, sub_l, ent_h, ent_l,
                                               out);
}

// Round 10
// 163.952 us; speedup vs baseline: 1.2027x; 1.2027x over previous
//
#include <hip/hip_runtime.h>
#include <hip/hip_bf16.h>
#include <math.h>

#define B_ 64
#define S_ 512
#define D_ 1024
#define H_ 512
#define WSEG 96
#define TSEG 24
#define CSEG 128
#define NSEG (WSEG + TSEG + CSEG) /* 248 */
#define ESEG (TSEG + CSEG + 1)    /* 153 */
#define EPAD 160                  /* ent rows padded per batch */

typedef __bf16 bf16x8 __attribute__((ext_vector_type(8)));
typedef __bf16 bf16x4 __attribute__((ext_vector_type(4)));
typedef float f32x4 __attribute__((ext_vector_type(4)));

#define GL16(g, l)                                                      \
  __builtin_amdgcn_global_load_lds(                                     \
      (const __attribute__((address_space(1))) void*)(g),               \
      (__attribute__((address_space(3))) void*)(l), 16, 0, 0)

__device__ inline float tanh_fast(float x) {
  const float xc = fminf(12.f, fmaxf(-12.f, x));
  const float e = __expf(2.f * xc);
  return (e - 1.f) * __builtin_amdgcn_rcpf(e + 1.f);
}

// ---------------------------------------------------------------------------
// Stage 1a: build CSR token lists per (b, segtype, seg). One block per b.
// ---------------------------------------------------------------------------
__global__ __launch_bounds__(512) void build_csr_kernel(
    const int* __restrict__ wseg, const int* __restrict__ tseg,
    const int* __restrict__ cseg, int* __restrict__ lw, int* __restrict__ lt,
    int* __restrict__ lc, int* __restrict__ meta) {
  __shared__ int wid[S_], tid_[S_], cid[S_];
  __shared__ int cw[WSEG], ct[TSEG], cc[CSEG];
  const int t = threadIdx.x;
  const int b = blockIdx.x;

  const int myw = wseg[b * S_ + t];
  const int myt = tseg[b * S_ + t];
  const int myc = cseg[b * S_ + t];
  wid[t] = myw;
  tid_[t] = myt;
  cid[t] = myc;
  if (t < WSEG) cw[t] = 0;
  if (t < TSEG) ct[t] = 0;
  if (t < CSEG) cc[t] = 0;
  __syncthreads();

  atomicAdd(&cw[myw], 1);
  atomicAdd(&ct[myt], 1);
  atomicAdd(&cc[myc], 1);
  __syncthreads();

  if (t == 0) {
    int r = 0;
    for (int i = 0; i < WSEG; ++i) {
      const int c = cw[i];
      meta[b * NSEG + i] = r | (c << 16);
      cw[i] = r;
      r += c;
    }
    r = 0;
    for (int i = 0; i < TSEG; ++i) {
      const int c = ct[i];
      meta[b * NSEG + WSEG + i] = r | (c << 16);
      ct[i] = r;
      r += c;
    }
    r = 0;
    for (int i = 0; i < CSEG; ++i) {
      const int c = cc[i];
      meta[b * NSEG + WSEG + TSEG + i] = r | (c << 16);
      cc[i] = r;
      r += c;
    }
  }
  __syncthreads();

  int rw = 0, rt = 0, rc = 0;
  for (int s = 0; s < S_; ++s) {
    const int below = (s < t) ? 1 : 0;
    rw += below & (wid[s] == myw);
    rt += below & (tid_[s] == myt);
    rc += below & (cid[s] == myc);
  }
  lw[b * S_ + cw[myw] + rw] = t;
  lt[b * S_ + ct[myt] + rt] = t;
  lc[b * S_ + cc[myc] + rc] = t;
}

// ---------------------------------------------------------------------------
// Stage 1b: per-row gather-sum (R6-proven, ~60us). One block per A row,
// 15872 blocks (max TLP); XCD swizzle as in R6. 3x logical q re-read rides
// L2/L3 at ~6.7 TB/s effective — measured better than both one-pass forms.
// ---------------------------------------------------------------------------
__global__ __launch_bounds__(256) void gather_rows_kernel(
    const float* __restrict__ q, const int* __restrict__ lw,
    const int* __restrict__ lt, const int* __restrict__ lc,
    const int* __restrict__ meta, __bf16* __restrict__ Ah,
    __bf16* __restrict__ Al) {
  __shared__ int slist[S_];
  const int t = threadIdx.x;
  const int bid = blockIdx.x;
  const int r = (bid & 7) * (B_ * NSEG / 8) + (bid >> 3);
  const int b = r / NSEG;
  const int seg = r % NSEG;

  const int m = meta[r];
  const int start = m & 0xFFFF;
  const int count = m >> 16;

  const int* list;
  int arow;
  if (seg < WSEG) {
    list = lw;
    arow = b * WSEG + seg;
  } else if (seg < WSEG + TSEG) {
    list = lt;
    arow = B_ * WSEG + b * TSEG + (seg - WSEG);
  } else {
    list = lc;
    arow = B_ * (WSEG + TSEG) + b * CSEG + (seg - WSEG - TSEG);
  }

  for (int i = t; i < count; i += 256) slist[i] = list[b * S_ + start + i];
  __syncthreads();

  const float* qb = q + (size_t)b * S_ * D_;
  float4 acc = make_float4(0.f, 0.f, 0.f, 0.f);
  int i = 0;
  for (; i + 2 <= count; i += 2) {
    const float4 a = *(const float4*)(qb + (size_t)slist[i] * D_ + (t << 2));
    const float4 c =
        *(const float4*)(qb + (size_t)slist[i + 1] * D_ + (t << 2));
    acc.x += a.x + c.x;
    acc.y += a.y + c.y;
    acc.z += a.z + c.z;
    acc.w += a.w + c.w;
  }
  if (i < count) {
    const float4 a = *(const float4*)(qb + (size_t)slist[i] * D_ + (t << 2));
    acc.x += a.x;
    acc.y += a.y;
    acc.z += a.z;
    acc.w += a.w;
  }
  const __bf16 h0 = (__bf16)acc.x, h1 = (__bf16)acc.y, h2 = (__bf16)acc.z,
               h3 = (__bf16)acc.w;
  const bf16x4 hv = {h0, h1, h2, h3};
  const bf16x4 lv = {(__bf16)(acc.x - (float)h0), (__bf16)(acc.y - (float)h1),
                     (__bf16)(acc.z - (float)h2), (__bf16)(acc.w - (float)h3)};
  *(bf16x4*)(Ah + (size_t)arow * D_ + (t << 2)) = hv;
  *(bf16x4*)(Al + (size_t)arow * D_ + (t << 2)) = lv;
}

// ---------------------------------------------------------------------------
// Stage 1c: transpose weights -> Wt hi/lo bf16 [3][512][1024].
// ---------------------------------------------------------------------------
__global__ __launch_bounds__(256) void prep_w_kernel(
    const float* __restrict__ Ws, const float* __restrict__ Wt_,
    const float* __restrict__ Wc, __bf16* __restrict__ Wth,
    __bf16* __restrict__ Wtl) {
  __shared__ float tile[64][65];
  const int z = blockIdx.z;
  const float* W = (z == 0) ? Ws : ((z == 1) ? Wt_ : Wc);
  const int k0 = blockIdx.y * 64, n0 = blockIdx.x * 64;
  const int tx = threadIdx.x & 63, ty = threadIdx.x >> 6;

#pragma unroll
  for (int i = 0; i < 16; ++i) {
    const int kl = i * 4 + ty;
    tile[kl][tx] = W[(size_t)(k0 + kl) * H_ + n0 + tx];
  }
  __syncthreads();
  __bf16* oh = Wth + (size_t)z * H_ * D_;
  __bf16* ol = Wtl + (size_t)z * H_ * D_;
#pragma unroll
  for (int i = 0; i < 16; ++i) {
    const int nl = i * 4 + ty;
    const float v = tile[tx][nl];
    const __bf16 h = (__bf16)v;
    oh[(size_t)(n0 + nl) * D_ + k0 + tx] = h;
    ol[(size_t)(n0 + nl) * D_ + k0 + tx] = (__bf16)(v - (float)h);
  }
}

// ---------------------------------------------------------------------------
// Stage 2: split-bf16 MFMA GEMM, 128x128 tile, BK=32, SINGLE 32KB buffer.
// R9 change: halve LDS (64->32KB) + __launch_bounds__(256,3) so 3 blocks/CU
// co-reside (12 waves/CU); cross-block overlap hides each block's barrier
// drain (m114 mechanism). Staging geometry = R7's validated BK=32 swizzle.
// ---------------------------------------------------------------------------
__global__ __launch_bounds__(256, 3) void gemm3_kernel(
    const __bf16* __restrict__ Ah, const __bf16* __restrict__ Al,
    const __bf16* __restrict__ Wth, const __bf16* __restrict__ Wtl,
    __bf16* __restrict__ sub_h, __bf16* __restrict__ sub_l,
    __bf16* __restrict__ ent_h, __bf16* __restrict__ ent_l, int m_offset) {
  // Ah@0, Al@8192, Bh@16384, Bl@24576 (each 128 rows x 64 B)
  __shared__ __align__(16) char smem[32768];

  const int tid = threadIdx.x;
  const int wid = tid >> 6;
  const int lane = tid & 63;
  const int m0 = m_offset + blockIdx.y * 128;
  const int n0 = blockIdx.x * 128;
  const int id = (m0 < B_ * WSEG) ? 0 : ((m0 < B_ * (WSEG + TSEG)) ? 1 : 2);

  const __bf16* Bh_g = Wth + (size_t)id * H_ * D_ + (size_t)n0 * D_;
  const __bf16* Bl_g = Wtl + (size_t)id * H_ * D_ + (size_t)n0 * D_;
  const __bf16* Ah_g = Ah + (size_t)m0 * D_;
  const __bf16* Al_g = Al + (size_t)m0 * D_;

  // staging: GL16 #i covers rows i*16+(lane>>2), slot lane&3; source chunk
  // pre-swizzled: g = (lane&3) ^ (row&3)   [R7-validated]
  const size_t grow_lane =
      (size_t)(lane >> 2) * D_ + (size_t)(((lane & 3) ^ ((lane >> 2) & 3)) * 8);

  const int wr = wid >> 1, wc = wid & 1;
  const int arow0 = wr * 64 + (lane & 15);
  const int brow0 = wc * 64 + (lane & 15);
  const int sx = (((lane >> 4) ^ (lane & 3)) << 4);  // swizzled 16B slot

  f32x4 acc[4][4] = {};

#pragma unroll 1
  for (int kt = 0; kt < D_ / 32; ++kt) {
    if (kt > 0) __syncthreads();  // previous compute done; LDS reusable
    {
      const size_t go = (size_t)kt * 32 + grow_lane;
#pragma unroll
      for (int jj = 0; jj < 2; ++jj) {
        const int i = wid * 2 + jj;
        const size_t gr = (size_t)i * 16 * D_ + go;
        GL16(Ah_g + gr, smem + i * 1024);
        GL16(Al_g + gr, smem + 8192 + i * 1024);
        GL16(Bh_g + gr, smem + 16384 + i * 1024);
        GL16(Bl_g + gr, smem + 24576 + i * 1024);
      }
    }
    __syncthreads();  // vmcnt(0) drain -> LDS valid

    bf16x8 ah[4], al_[4], bh[4], bl_[4];
#pragma unroll
    for (int mi = 0; mi < 4; ++mi) {
      const int off = (arow0 + mi * 16) * 64 + sx;
      ah[mi] = *(const bf16x8*)(smem + off);
      al_[mi] = *(const bf16x8*)(smem + 8192 + off);
    }
#pragma unroll
    for (int ni = 0; ni < 4; ++ni) {
      const int off = (brow0 + ni * 16) * 64 + sx;
      bh[ni] = *(const bf16x8*)(smem + 16384 + off);
      bl_[ni] = *(const bf16x8*)(smem + 24576 + off);
    }
#pragma unroll
    for (int mi = 0; mi < 4; ++mi)
#pragma unroll
      for (int ni = 0; ni < 4; ++ni) {
        acc[mi][ni] = __builtin_amdgcn_mfma_f32_16x16x32_bf16(
            ah[mi], bh[ni], acc[mi][ni], 0, 0, 0);
        acc[mi][ni] = __builtin_amdgcn_mfma_f32_16x16x32_bf16(
            ah[mi], bl_[ni], acc[mi][ni], 0, 0, 0);
        acc[mi][ni] = __builtin_amdgcn_mfma_f32_16x16x32_bf16(
            al_[mi], bh[ni], acc[mi][ni], 0, 0, 0);
      }
  }

  const int rowb = m0 + wr * 64 + (lane >> 4) * 4;
  const int colb = n0 + wc * 64 + (lane & 15);
#pragma unroll
  for (int mi = 0; mi < 4; ++mi)
#pragma unroll
    for (int ni = 0; ni < 4; ++ni) {
      const f32x4 v = acc[mi][ni];
      const int col = colb + ni * 16;
#pragma unroll
      for (int r = 0; r < 4; ++r) {
        const int row = rowb + mi * 16 + r;
        const float val = tanh_fast(v[r]);
        const __bf16 h = (__bf16)val;
        const __bf16 l = (__bf16)(val - (float)h);
        size_t oix;
        __bf16 *oh, *ol;
        if (id == 0) {
          oix = (size_t)row * H_ + col;
          oh = sub_h;
          ol = sub_l;
        } else if (id == 1) {
          const int lr = row - B_ * WSEG;
          const int bb = lr / TSEG;
          const int rr = lr - bb * TSEG;
          oix = ((size_t)bb * EPAD + rr) * H_ + col;
          oh = ent_h;
          ol = ent_l;
        } else {
          const int lr = row - B_ * (WSEG + TSEG);
          const int bb = lr >> 7;
          const int rr = lr & 127;
          oix = ((size_t)bb * EPAD + TSEG + rr) * H_ + col;
          oh = ent_h;
          ol = ent_l;
        }
        oh[oix] = h;
        ol[oix] = l;
      }
    }
}

// Stage 2b: ent row 152 = no_entry (hi/lo, raw); rows 153..159 zeroed.
__global__ __launch_bounds__(512) void ne_fill_kernel(
    const float* __restrict__ ne, __bf16* __restrict__ ent_h,
    __bf16* __restrict__ ent_l) {
  const int h = threadIdx.x;
  const int b = blockIdx.x;
  const float v = ne[h];
  const __bf16 hi = (__bf16)v;
  const __bf16 lo = (__bf16)(v - (float)hi);
  ent_h[((size_t)b * EPAD + 152) * H_ + h] = hi;
  ent_l[((size_t)b * EPAD + 152) * H_ + h] = lo;
#pragma unroll
  for (int r = 153; r < EPAD; ++r) {
    ent_h[((size_t)b * EPAD + r) * H_ + h] = (__bf16)0.f;
    ent_l[((size_t)b * EPAD + r) * H_ + h] = (__bf16)0.f;
  }
}

// ---------------------------------------------------------------------------
// Stage 3: att = softmax(sub @ ent^T) via split-bf16 MFMA.
// Grid = B*2 (2 blocks/batch, 48 rows each), 192 thr (3 waves).
// ---------------------------------------------------------------------------
__global__ __launch_bounds__(192) void attn_mfma_kernel(
    const __bf16* __restrict__ sub_h, const __bf16* __restrict__ sub_l,
    const __bf16* __restrict__ ent_h, const __bf16* __restrict__ ent_l,
    float* __restrict__ out) {
  __shared__ __align__(16) char smem[53248];
  char* sSh = smem;           // [48][64] bf16: 6 KB
  char* sSl = smem + 6144;    // 6 KB
  char* sEh = smem + 12288;   // [160][64] bf16: 20 KB
  char* sEl = smem + 32768;   // 20 KB

  const int tid = threadIdx.x;
  const int wid = tid >> 6;
  const int lane = tid & 63;
  const int b = blockIdx.x >> 1;
  const int half = blockIdx.x & 1;

  const __bf16* Sh_g = sub_h + ((size_t)b * WSEG + half * 48) * H_;
  const __bf16* Sl_g = sub_l + ((size_t)b * WSEG + half * 48) * H_;
  const __bf16* Eh_g = ent_h + (size_t)b * EPAD * H_;
  const __bf16* El_g = ent_l + (size_t)b * EPAD * H_;

  const int rsub = lane >> 3;
  const int csrc = (lane & 7) ^ rsub;

  const int arow0 = wid * 16 + (lane & 15);
  const int brow0 = lane & 15;
  const int cbase = (lane >> 4) * 16;
  const int sw = (lane & 7) << 4;

  f32x4 acc[10] = {};

#pragma unroll 1
  for (int kt = 0; kt < H_ / 64; ++kt) {
    __syncthreads();
    const size_t kofs = (size_t)kt * 64 + (size_t)csrc * 8;
#pragma unroll
    for (int j = 0; j < 18; ++j) {
      const int ig = wid * 18 + j;
      if (ig < 6) {
        GL16(Sh_g + (size_t)(ig * 8 + rsub) * H_ + kofs, sSh + ig * 1024);
      } else if (ig < 12) {
        const int i = ig - 6;
        GL16(Sl_g + (size_t)(i * 8 + rsub) * H_ + kofs, sSl + i * 1024);
      } else if (ig < 32) {
        const int i = ig - 12;
        GL16(Eh_g + (size_t)(i * 8 + rsub) * H_ + kofs, sEh + i * 1024);
      } else if (ig < 52) {
        const int i = ig - 32;
        GL16(El_g + (size_t)(i * 8 + rsub) * H_ + kofs, sEl + i * 1024);
      }
    }
    __syncthreads();

#pragma unroll
    for (int ks = 0; ks < 2; ++ks) {
      const int cc = ((cbase + ks * 64) ^ sw);
      const int aoff = arow0 * 128 + cc;
      const bf16x8 ah = *(const bf16x8*)(sSh + aoff);
      const bf16x8 al_ = *(const bf16x8*)(sSl + aoff);
#pragma unroll
      for (int ni = 0; ni < 10; ++ni) {
        const int off = (brow0 + ni * 16) * 128 + cc;
        const bf16x8 bh = *(const bf16x8*)(sEh + off);
        const bf16x8 bl_ = *(const bf16x8*)(sEl + off);
        acc[ni] = __builtin_amdgcn_mfma_f32_16x16x32_bf16(ah, bh, acc[ni], 0,
                                                          0, 0);
        acc[ni] = __builtin_amdgcn_mfma_f32_16x16x32_bf16(ah, bl_, acc[ni], 0,
                                                          0, 0);
        acc[ni] = __builtin_amdgcn_mfma_f32_16x16x32_bf16(al_, bh, acc[ni], 0,
                                                          0, 0);
      }
    }
  }

  __syncthreads();
  float (*lg)[EPAD] = (float(*)[EPAD])smem;  // 48*160*4 = 30720 B
  const int rowb = wid * 16 + (lane >> 4) * 4;
  const int colb = lane & 15;
#pragma unroll
  for (int ni = 0; ni < 10; ++ni) {
    const f32x4 v = acc[ni];
#pragma unroll
    for (int r = 0; r < 4; ++r) lg[rowb + r][colb + ni * 16] = v[r];
  }
  __syncthreads();

  for (int r = wid; r < 48; r += 3) {
    const float x0 = lg[r][lane];
    const float x1 = lg[r][lane + 64];
    const bool has2 = (lane + 128) < ESEG;
    const float x2 = has2 ? lg[r][lane + 128] : -INFINITY;
    float m = fmaxf(fmaxf(x0, x1), x2);
#pragma unroll
    for (int off = 32; off >= 1; off >>= 1) m = fmaxf(m, __shfl_xor(m, off, 64));
    const float p0 = expf(x0 - m);
    const float p1 = expf(x1 - m);
    const float p2 = has2 ? expf(x2 - m) : 0.f;
    float ssum = p0 + p1 + p2;
#pragma unroll
    for (int off = 32; off >= 1; off >>= 1) ssum += __shfl_xor(ssum, off, 64);
    const float inv = 1.f / ssum;
    float* ob = out + ((size_t)(b * WSEG + half * 48 + r)) * ESEG;
    ob[lane] = p0 * inv;
    ob[lane + 64] = p1 * inv;
    if (has2) ob[lane + 128] = p2 * inv;
  }
}

// ---------------------------------------------------------------------------
extern "C" void kernel_launch(void* const* d_in, const int* in_sizes, int n_in,
                              void* d_out, int out_size, void* d_ws,
                              size_t ws_size, hipStream_t stream) {
  const float* q = (const float*)d_in[0];
  const float* Wsub = (const float*)d_in[1];
  const float* Wtab = (const float*)d_in[2];
  const float* Wcol = (const float*)d_in[3];
  const float* ne = (const float*)d_in[4];
  const int* wseg = (const int*)d_in[5];
  const int* tseg = (const int*)d_in[6];
  const int* cseg = (const int*)d_in[7];
  float* out = (float*)d_out;

  // flat workspace layout (~105MB of the ~512MB ws)
  char* w = (char*)d_ws;
  __bf16* Ah = (__bf16*)(w);                 // 32,505,856
  __bf16* Al = (__bf16*)(w + 32505856);      // 32,505,856
  __bf16* ent_h = (__bf16*)(w + 65011712);   // 10,485,760
  __bf16* ent_l = (__bf16*)(w + 75497472);   // 10,485,760
  __bf16* Wth = (__bf16*)(w + 85983232);     //  3,145,728
  __bf16* Wtl = (__bf16*)(w + 89128960);     //  3,145,728
  __bf16* sub_h = (__bf16*)(w + 92274688);   //  6,291,456
  __bf16* sub_l = (__bf16*)(w + 98566144);   //  6,291,456
  int* lw = (int*)(w + 104857600);
  int* lt = (int*)(w + 104988672);
  int* lc = (int*)(w + 105119744);
  int* meta = (int*)(w + 105250816);

  build_csr_kernel<<<B_, 512, 0, stream>>>(wseg, tseg, cseg, lw, lt, lc, meta);
  gather_rows_kernel<<<B_ * NSEG, 256, 0, stream>>>(q, lw, lt, lc, meta, Ah,
                                                    Al);
  prep_w_kernel<<<dim3(8, 16, 3), 256, 0, stream>>>(Wsub, Wtab, Wcol, Wth,
                                                    Wtl);
  gemm3_kernel<<<dim3(4, 124), 256, 0, stream>>>(Ah, Al, Wth, Wtl, sub_h,
                                                 sub_l, ent_h, ent_l, 0);
  ne_fill_kernel<<<B_, 512, 0, stream>>>(ne, ent_h, ent_l);
  attn_mfma_kernel<<<B_ * 2, 192, 0, stream>>>(sub_h, sub_l, ent_h, ent_l,
                                               out);
}

// Round 11
// 151.767 us; speedup vs baseline: 1.2992x; 1.0803x over previous
//
#include <hip/hip_runtime.h>
#include <hip/hip_bf16.h>
#include <math.h>

#define B_ 64
#define S_ 512
#define D_ 1024
#define H_ 512
#define WSEG 96
#define TSEG 24
#define CSEG 128
#define NSEG (WSEG + TSEG + CSEG) /* 248 */
#define ESEG (TSEG + CSEG + 1)    /* 153 */
#define EPAD 160                  /* ent rows padded per batch */

typedef __bf16 bf16x8 __attribute__((ext_vector_type(8)));
typedef __bf16 bf16x4 __attribute__((ext_vector_type(4)));
typedef float f32x4 __attribute__((ext_vector_type(4)));

#define GL16(g, l)                                                      \
  __builtin_amdgcn_global_load_lds(                                     \
      (const __attribute__((address_space(1))) void*)(g),               \
      (__attribute__((address_space(3))) void*)(l), 16, 0, 0)

__device__ inline float tanh_fast(float x) {
  const float xc = fminf(12.f, fmaxf(-12.f, x));
  const float e = __expf(2.f * xc);
  return (e - 1.f) * __builtin_amdgcn_rcpf(e + 1.f);
}

// ---------------------------------------------------------------------------
// Stage 1a: build CSR token lists per (b, segtype, seg). One block per b.
// ---------------------------------------------------------------------------
__global__ __launch_bounds__(512) void build_csr_kernel(
    const int* __restrict__ wseg, const int* __restrict__ tseg,
    const int* __restrict__ cseg, int* __restrict__ lw, int* __restrict__ lt,
    int* __restrict__ lc, int* __restrict__ meta) {
  __shared__ int wid[S_], tid_[S_], cid[S_];
  __shared__ int cw[WSEG], ct[TSEG], cc[CSEG];
  const int t = threadIdx.x;
  const int b = blockIdx.x;

  const int myw = wseg[b * S_ + t];
  const int myt = tseg[b * S_ + t];
  const int myc = cseg[b * S_ + t];
  wid[t] = myw;
  tid_[t] = myt;
  cid[t] = myc;
  if (t < WSEG) cw[t] = 0;
  if (t < TSEG) ct[t] = 0;
  if (t < CSEG) cc[t] = 0;
  __syncthreads();

  atomicAdd(&cw[myw], 1);
  atomicAdd(&ct[myt], 1);
  atomicAdd(&cc[myc], 1);
  __syncthreads();

  if (t == 0) {
    int r = 0;
    for (int i = 0; i < WSEG; ++i) {
      const int c = cw[i];
      meta[b * NSEG + i] = r | (c << 16);
      cw[i] = r;
      r += c;
    }
    r = 0;
    for (int i = 0; i < TSEG; ++i) {
      const int c = ct[i];
      meta[b * NSEG + WSEG + i] = r | (c << 16);
      ct[i] = r;
      r += c;
    }
    r = 0;
    for (int i = 0; i < CSEG; ++i) {
      const int c = cc[i];
      meta[b * NSEG + WSEG + TSEG + i] = r | (c << 16);
      cc[i] = r;
      r += c;
    }
  }
  __syncthreads();

  int rw = 0, rt = 0, rc = 0;
  for (int s = 0; s < S_; ++s) {
    const int below = (s < t) ? 1 : 0;
    rw += below & (wid[s] == myw);
    rt += below & (tid_[s] == myt);
    rc += below & (cid[s] == myc);
  }
  lw[b * S_ + cw[myw] + rw] = t;
  lt[b * S_ + ct[myt] + rt] = t;
  lc[b * S_ + cc[myc] + rc] = t;
}

// ---------------------------------------------------------------------------
// Stage 1b: per-row gather-sum (R6-proven, ~60us, fabric-floor-bound).
// ---------------------------------------------------------------------------
__global__ __launch_bounds__(256) void gather_rows_kernel(
    const float* __restrict__ q, const int* __restrict__ lw,
    const int* __restrict__ lt, const int* __restrict__ lc,
    const int* __restrict__ meta, __bf16* __restrict__ Ah,
    __bf16* __restrict__ Al) {
  __shared__ int slist[S_];
  const int t = threadIdx.x;
  const int bid = blockIdx.x;
  const int r = (bid & 7) * (B_ * NSEG / 8) + (bid >> 3);
  const int b = r / NSEG;
  const int seg = r % NSEG;

  const int m = meta[r];
  const int start = m & 0xFFFF;
  const int count = m >> 16;

  const int* list;
  int arow;
  if (seg < WSEG) {
    list = lw;
    arow = b * WSEG + seg;
  } else if (seg < WSEG + TSEG) {
    list = lt;
    arow = B_ * WSEG + b * TSEG + (seg - WSEG);
  } else {
    list = lc;
    arow = B_ * (WSEG + TSEG) + b * CSEG + (seg - WSEG - TSEG);
  }

  for (int i = t; i < count; i += 256) slist[i] = list[b * S_ + start + i];
  __syncthreads();

  const float* qb = q + (size_t)b * S_ * D_;
  float4 acc = make_float4(0.f, 0.f, 0.f, 0.f);
  int i = 0;
  for (; i + 2 <= count; i += 2) {
    const float4 a = *(const float4*)(qb + (size_t)slist[i] * D_ + (t << 2));
    const float4 c =
        *(const float4*)(qb + (size_t)slist[i + 1] * D_ + (t << 2));
    acc.x += a.x + c.x;
    acc.y += a.y + c.y;
    acc.z += a.z + c.z;
    acc.w += a.w + c.w;
  }
  if (i < count) {
    const float4 a = *(const float4*)(qb + (size_t)slist[i] * D_ + (t << 2));
    acc.x += a.x;
    acc.y += a.y;
    acc.z += a.z;
    acc.w += a.w;
  }
  const __bf16 h0 = (__bf16)acc.x, h1 = (__bf16)acc.y, h2 = (__bf16)acc.z,
               h3 = (__bf16)acc.w;
  const bf16x4 hv = {h0, h1, h2, h3};
  const bf16x4 lv = {(__bf16)(acc.x - (float)h0), (__bf16)(acc.y - (float)h1),
                     (__bf16)(acc.z - (float)h2), (__bf16)(acc.w - (float)h3)};
  *(bf16x4*)(Ah + (size_t)arow * D_ + (t << 2)) = hv;
  *(bf16x4*)(Al + (size_t)arow * D_ + (t << 2)) = lv;
}

// ---------------------------------------------------------------------------
// Stage 1c: transpose weights -> Wt hi/lo bf16 [3][512][1024].
// ---------------------------------------------------------------------------
__global__ __launch_bounds__(256) void prep_w_kernel(
    const float* __restrict__ Ws, const float* __restrict__ Wt_,
    const float* __restrict__ Wc, __bf16* __restrict__ Wth,
    __bf16* __restrict__ Wtl) {
  __shared__ float tile[64][65];
  const int z = blockIdx.z;
  const float* W = (z == 0) ? Ws : ((z == 1) ? Wt_ : Wc);
  const int k0 = blockIdx.y * 64, n0 = blockIdx.x * 64;
  const int tx = threadIdx.x & 63, ty = threadIdx.x >> 6;

#pragma unroll
  for (int i = 0; i < 16; ++i) {
    const int kl = i * 4 + ty;
    tile[kl][tx] = W[(size_t)(k0 + kl) * H_ + n0 + tx];
  }
  __syncthreads();
  __bf16* oh = Wth + (size_t)z * H_ * D_;
  __bf16* ol = Wtl + (size_t)z * H_ * D_;
#pragma unroll
  for (int i = 0; i < 16; ++i) {
    const int nl = i * 4 + ty;
    const float v = tile[tx][nl];
    const __bf16 h = (__bf16)v;
    oh[(size_t)(n0 + nl) * D_ + k0 + tx] = h;
    ol[(size_t)(n0 + nl) * D_ + k0 + tx] = (__bf16)(v - (float)h);
  }
}

// ---------------------------------------------------------------------------
// Stage 2: split-bf16 MFMA GEMM, 128x128 tile, BK=64 (R6-proven structure).
// R10 change: bijective XCD swizzle of the 496-block grid so the 4 N-sibling
// blocks sharing an A-panel land on the SAME XCD (A re-reads become L2 hits
// instead of L3). lin = bx + by*4; logical = (lin&7)*62 + (lin>>3).
// ---------------------------------------------------------------------------
__global__ __launch_bounds__(256) void gemm3_kernel(
    const __bf16* __restrict__ Ah, const __bf16* __restrict__ Al,
    const __bf16* __restrict__ Wth, const __bf16* __restrict__ Wtl,
    __bf16* __restrict__ sub_h, __bf16* __restrict__ sub_l,
    __bf16* __restrict__ ent_h, __bf16* __restrict__ ent_l) {
  __shared__ __align__(16) char smem[65536];
  char* sAh = smem;
  char* sAl = smem + 16384;
  char* sBh = smem + 32768;
  char* sBl = smem + 49152;

  const int tid = threadIdx.x;
  const int wid = tid >> 6;
  const int lane = tid & 63;
  // XCD swizzle: launched linear -> logical block (496 = 8 * 62, bijective)
  const int lin = blockIdx.x + blockIdx.y * 4;
  const int logical = (lin & 7) * 62 + (lin >> 3);
  const int m0 = (logical >> 2) * 128;
  const int n0 = (logical & 3) * 128;
  const int id = (m0 < B_ * WSEG) ? 0 : ((m0 < B_ * (WSEG + TSEG)) ? 1 : 2);

  const __bf16* Bh_g = Wth + (size_t)id * H_ * D_ + (size_t)n0 * D_;
  const __bf16* Bl_g = Wtl + (size_t)id * H_ * D_ + (size_t)n0 * D_;
  const __bf16* Ah_g = Ah + (size_t)m0 * D_;
  const __bf16* Al_g = Al + (size_t)m0 * D_;

  const int rsub = lane >> 3;
  const int csrc = (lane & 7) ^ rsub;

  const int wr = wid >> 1, wc = wid & 1;
  const int arow0 = wr * 64 + (lane & 15);
  const int brow0 = wc * 64 + (lane & 15);
  const int cbase = (lane >> 4) * 16;
  const int sw = (lane & 7) << 4;

  f32x4 acc[4][4] = {};

#pragma unroll 1
  for (int kt = 0; kt < D_ / 64; ++kt) {
    __syncthreads();
    const size_t kofs = (size_t)kt * 64 + (size_t)csrc * 8;
#pragma unroll
    for (int j = 0; j < 4; ++j) {
      const int i = wid * 4 + j;
      const size_t grow = (size_t)(i * 8 + rsub) * D_ + kofs;
      GL16(Ah_g + grow, sAh + i * 1024);
      GL16(Al_g + grow, sAl + i * 1024);
      GL16(Bh_g + grow, sBh + i * 1024);
      GL16(Bl_g + grow, sBl + i * 1024);
    }
    __syncthreads();

#pragma unroll
    for (int ks = 0; ks < 2; ++ks) {
      const int cc = ((cbase + ks * 64) ^ sw);
      bf16x8 ah[4], al_[4], bh[4], bl_[4];
#pragma unroll
      for (int mi = 0; mi < 4; ++mi) {
        const int off = (arow0 + mi * 16) * 128 + cc;
        ah[mi] = *(const bf16x8*)(sAh + off);
        al_[mi] = *(const bf16x8*)(sAl + off);
      }
#pragma unroll
      for (int ni = 0; ni < 4; ++ni) {
        const int off = (brow0 + ni * 16) * 128 + cc;
        bh[ni] = *(const bf16x8*)(sBh + off);
        bl_[ni] = *(const bf16x8*)(sBl + off);
      }
#pragma unroll
      for (int mi = 0; mi < 4; ++mi)
#pragma unroll
        for (int ni = 0; ni < 4; ++ni) {
          acc[mi][ni] = __builtin_amdgcn_mfma_f32_16x16x32_bf16(
              ah[mi], bh[ni], acc[mi][ni], 0, 0, 0);
          acc[mi][ni] = __builtin_amdgcn_mfma_f32_16x16x32_bf16(
              ah[mi], bl_[ni], acc[mi][ni], 0, 0, 0);
          acc[mi][ni] = __builtin_amdgcn_mfma_f32_16x16x32_bf16(
              al_[mi], bh[ni], acc[mi][ni], 0, 0, 0);
        }
    }
  }

  const int rowb = m0 + wr * 64 + (lane >> 4) * 4;
  const int colb = n0 + wc * 64 + (lane & 15);
#pragma unroll
  for (int mi = 0; mi < 4; ++mi)
#pragma unroll
    for (int ni = 0; ni < 4; ++ni) {
      const f32x4 v = acc[mi][ni];
      const int col = colb + ni * 16;
#pragma unroll
      for (int r = 0; r < 4; ++r) {
        const int row = rowb + mi * 16 + r;
        const float val = tanh_fast(v[r]);
        const __bf16 h = (__bf16)val;
        const __bf16 l = (__bf16)(val - (float)h);
        size_t oix;
        __bf16 *oh, *ol;
        if (id == 0) {
          oix = (size_t)row * H_ + col;
          oh = sub_h;
          ol = sub_l;
        } else if (id == 1) {
          const int lr = row - B_ * WSEG;
          const int bb = lr / TSEG;
          const int rr = lr - bb * TSEG;
          oix = ((size_t)bb * EPAD + rr) * H_ + col;
          oh = ent_h;
          ol = ent_l;
        } else {
          const int lr = row - B_ * (WSEG + TSEG);
          const int bb = lr >> 7;
          const int rr = lr & 127;
          oix = ((size_t)bb * EPAD + TSEG + rr) * H_ + col;
          oh = ent_h;
          ol = ent_l;
        }
        oh[oix] = h;
        ol[oix] = l;
      }
    }
}

// Stage 2b: ent row 152 = no_entry (hi/lo, raw); rows 153..159 zeroed.
__global__ __launch_bounds__(512) void ne_fill_kernel(
    const float* __restrict__ ne, __bf16* __restrict__ ent_h,
    __bf16* __restrict__ ent_l) {
  const int h = threadIdx.x;
  const int b = blockIdx.x;
  const float v = ne[h];
  const __bf16 hi = (__bf16)v;
  const __bf16 lo = (__bf16)(v - (float)hi);
  ent_h[((size_t)b * EPAD + 152) * H_ + h] = hi;
  ent_l[((size_t)b * EPAD + 152) * H_ + h] = lo;
#pragma unroll
  for (int r = 153; r < EPAD; ++r) {
    ent_h[((size_t)b * EPAD + r) * H_ + h] = (__bf16)0.f;
    ent_l[((size_t)b * EPAD + r) * H_ + h] = (__bf16)0.f;
  }
}

// ---------------------------------------------------------------------------
// Stage 3: att = softmax(sub @ ent^T) via split-bf16 MFMA.
// Grid = B*2 (2 blocks/batch, 48 rows each), 192 thr (3 waves).
// ---------------------------------------------------------------------------
__global__ __launch_bounds__(192) void attn_mfma_kernel(
    const __bf16* __restrict__ sub_h, const __bf16* __restrict__ sub_l,
    const __bf16* __restrict__ ent_h, const __bf16* __restrict__ ent_l,
    float* __restrict__ out) {
  __shared__ __align__(16) char smem[53248];
  char* sSh = smem;           // [48][64] bf16: 6 KB
  char* sSl = smem + 6144;    // 6 KB
  char* sEh = smem + 12288;   // [160][64] bf16: 20 KB
  char* sEl = smem + 32768;   // 20 KB

  const int tid = threadIdx.x;
  const int wid = tid >> 6;
  const int lane = tid & 63;
  const int b = blockIdx.x >> 1;
  const int half = blockIdx.x & 1;

  const __bf16* Sh_g = sub_h + ((size_t)b * WSEG + half * 48) * H_;
  const __bf16* Sl_g = sub_l + ((size_t)b * WSEG + half * 48) * H_;
  const __bf16* Eh_g = ent_h + (size_t)b * EPAD * H_;
  const __bf16* El_g = ent_l + (size_t)b * EPAD * H_;

  const int rsub = lane >> 3;
  const int csrc = (lane & 7) ^ rsub;

  const int arow0 = wid * 16 + (lane & 15);
  const int brow0 = lane & 15;
  const int cbase = (lane >> 4) * 16;
  const int sw = (lane & 7) << 4;

  f32x4 acc[10] = {};

#pragma unroll 1
  for (int kt = 0; kt < H_ / 64; ++kt) {
    __syncthreads();
    const size_t kofs = (size_t)kt * 64 + (size_t)csrc * 8;
#pragma unroll
    for (int j = 0; j < 18; ++j) {
      const int ig = wid * 18 + j;
      if (ig < 6) {
        GL16(Sh_g + (size_t)(ig * 8 + rsub) * H_ + kofs, sSh + ig * 1024);
      } else if (ig < 12) {
        const int i = ig - 6;
        GL16(Sl_g + (size_t)(i * 8 + rsub) * H_ + kofs, sSl + i * 1024);
      } else if (ig < 32) {
        const int i = ig - 12;
        GL16(Eh_g + (size_t)(i * 8 + rsub) * H_ + kofs, sEh + i * 1024);
      } else if (ig < 52) {
        const int i = ig - 32;
        GL16(El_g + (size_t)(i * 8 + rsub) * H_ + kofs, sEl + i * 1024);
      }
    }
    __syncthreads();

#pragma unroll
    for (int ks = 0; ks < 2; ++ks) {
      const int cc = ((cbase + ks * 64) ^ sw);
      const int aoff = arow0 * 128 + cc;
      const bf16x8 ah = *(const bf16x8*)(sSh + aoff);
      const bf16x8 al_ = *(const bf16x8*)(sSl + aoff);
#pragma unroll
      for (int ni = 0; ni < 10; ++ni) {
        const int off = (brow0 + ni * 16) * 128 + cc;
        const bf16x8 bh = *(const bf16x8*)(sEh + off);
        const bf16x8 bl_ = *(const bf16x8*)(sEl + off);
        acc[ni] = __builtin_amdgcn_mfma_f32_16x16x32_bf16(ah, bh, acc[ni], 0,
                                                          0, 0);
        acc[ni] = __builtin_amdgcn_mfma_f32_16x16x32_bf16(ah, bl_, acc[ni], 0,
                                                          0, 0);
        acc[ni] = __builtin_amdgcn_mfma_f32_16x16x32_bf16(al_, bh, acc[ni], 0,
                                                          0, 0);
      }
    }
  }

  __syncthreads();
  float (*lg)[EPAD] = (float(*)[EPAD])smem;  // 48*160*4 = 30720 B
  const int rowb = wid * 16 + (lane >> 4) * 4;
  const int colb = lane & 15;
#pragma unroll
  for (int ni = 0; ni < 10; ++ni) {
    const f32x4 v = acc[ni];
#pragma unroll
    for (int r = 0; r < 4; ++r) lg[rowb + r][colb + ni * 16] = v[r];
  }
  __syncthreads();

  for (int r = wid; r < 48; r += 3) {
    const float x0 = lg[r][lane];
    const float x1 = lg[r][lane + 64];
    const bool has2 = (lane + 128) < ESEG;
    const float x2 = has2 ? lg[r][lane + 128] : -INFINITY;
    float m = fmaxf(fmaxf(x0, x1), x2);
#pragma unroll
    for (int off = 32; off >= 1; off >>= 1) m = fmaxf(m, __shfl_xor(m, off, 64));
    const float p0 = expf(x0 - m);
    const float p1 = expf(x1 - m);
    const float p2 = has2 ? expf(x2 - m) : 0.f;
    float ssum = p0 + p1 + p2;
#pragma unroll
    for (int off = 32; off >= 1; off >>= 1) ssum += __shfl_xor(ssum, off, 64);
    const float inv = 1.f / ssum;
    float* ob = out + ((size_t)(b * WSEG + half * 48 + r)) * ESEG;
    ob[lane] = p0 * inv;
    ob[lane + 64] = p1 * inv;
    if (has2) ob[lane + 128] = p2 * inv;
  }
}

// ---------------------------------------------------------------------------
extern "C" void kernel_launch(void* const* d_in, const int* in_sizes, int n_in,
                              void* d_out, int out_size, void* d_ws,
                              size_t ws_size, hipStream_t stream) {
  const float* q = (const float*)d_in[0];
  const float* Wsub = (const float*)d_in[1];
  const float* Wtab = (const float*)d_in[2];
  const float* Wcol = (const float*)d_in[3];
  const float* ne = (const float*)d_in[4];
  const int* wseg = (const int*)d_in[5];
  const int* tseg = (const int*)d_in[6];
  const int* cseg = (const int*)d_in[7];
  float* out = (float*)d_out;

  // flat workspace layout (~105MB of the ~512MB ws)
  char* w = (char*)d_ws;
  __bf16* Ah = (__bf16*)(w);                 // 32,505,856
  __bf16* Al = (__bf16*)(w + 32505856);      // 32,505,856
  __bf16* ent_h = (__bf16*)(w + 65011712);   // 10,485,760
  __bf16* ent_l = (__bf16*)(w + 75497472);   // 10,485,760
  __bf16* Wth = (__bf16*)(w + 85983232);     //  3,145,728
  __bf16* Wtl = (__bf16*)(w + 89128960);     //  3,145,728
  __bf16* sub_h = (__bf16*)(w + 92274688);   //  6,291,456
  __bf16* sub_l = (__bf16*)(w + 98566144);   //  6,291,456
  int* lw = (int*)(w + 104857600);
  int* lt = (int*)(w + 104988672);
  int* lc = (int*)(w + 105119744);
  int* meta = (int*)(w + 105250816);

  build_csr_kernel<<<B_, 512, 0, stream>>>(wseg, tseg, cseg, lw, lt, lc, meta);
  gather_rows_kernel<<<B_ * NSEG, 256, 0, stream>>>(q, lw, lt, lc, meta, Ah,
                                                    Al);
  prep_w_kernel<<<dim3(8, 16, 3), 256, 0, stream>>>(Wsub, Wtab, Wcol, Wth,
                                                    Wtl);
  gemm3_kernel<<<dim3(4, 124), 256, 0, stream>>>(Ah, Al, Wth, Wtl, sub_h,
                                                 sub_l, ent_h, ent_l);
  ne_fill_kernel<<<B_, 512, 0, stream>>>(ne, ent_h, ent_l);
  attn_mfma_kernel<<<B_ * 2, 192, 0, stream>>>(sub_h, sub_l, ent_h, ent_l,
                                               out);
}

// Round 12
// 146.369 us; speedup vs baseline: 1.3471x; 1.0369x over previous
//
#include <hip/hip_runtime.h>
#include <hip/hip_bf16.h>
#include <math.h>

#define B_ 64
#define S_ 512
#define D_ 1024
#define H_ 512
#define WSEG 96
#define TSEG 24
#define CSEG 128
#define NSEG (WSEG + TSEG + CSEG) /* 248 */
#define ESEG (TSEG + CSEG + 1)    /* 153 */
#define EPAD 160                  /* ent rows padded per batch */

typedef __bf16 bf16x8 __attribute__((ext_vector_type(8)));
typedef __bf16 bf16x4 __attribute__((ext_vector_type(4)));
typedef float f32x4 __attribute__((ext_vector_type(4)));

#define GL16(g, l)                                                      \
  __builtin_amdgcn_global_load_lds(                                     \
      (const __attribute__((address_space(1))) void*)(g),               \
      (__attribute__((address_space(3))) void*)(l), 16, 0, 0)

__device__ inline float tanh_fast(float x) {
  const float xc = fminf(12.f, fmaxf(-12.f, x));
  const float e = __expf(2.f * xc);
  return (e - 1.f) * __builtin_amdgcn_rcpf(e + 1.f);
}

// ---------------------------------------------------------------------------
// Stage 1 (merged setup): blocks 0..63 = CSR build (one per batch);
// blocks 64..447 = weight transpose/split; blocks 448..511 = ne fill.
// All three are mutually independent -> one launch, overlapped execution.
// ---------------------------------------------------------------------------
__global__ __launch_bounds__(512) void setup_kernel(
    const int* __restrict__ wseg, const int* __restrict__ tseg,
    const int* __restrict__ cseg, const float* __restrict__ Ws,
    const float* __restrict__ Wt_, const float* __restrict__ Wc,
    const float* __restrict__ ne, int* __restrict__ lw, int* __restrict__ lt,
    int* __restrict__ lc, int* __restrict__ meta, __bf16* __restrict__ Wth,
    __bf16* __restrict__ Wtl, __bf16* __restrict__ ent_h,
    __bf16* __restrict__ ent_l) {
  __shared__ int wid[S_], tid_[S_], cid[S_];
  __shared__ int cw[WSEG], ct[TSEG], ccnt[CSEG];
  __shared__ float tile[64][65];
  const int blk = blockIdx.x;
  const int t = threadIdx.x;

  if (blk < 64) {
    // ---- CSR build, b = blk ----
    const int b = blk;
    const int myw = wseg[b * S_ + t];
    const int myt = tseg[b * S_ + t];
    const int myc = cseg[b * S_ + t];
    wid[t] = myw;
    tid_[t] = myt;
    cid[t] = myc;
    if (t < WSEG) cw[t] = 0;
    if (t < TSEG) ct[t] = 0;
    if (t < CSEG) ccnt[t] = 0;
    __syncthreads();

    atomicAdd(&cw[myw], 1);
    atomicAdd(&ct[myt], 1);
    atomicAdd(&ccnt[myc], 1);
    __syncthreads();

    if (t == 0) {
      int r = 0;
      for (int i = 0; i < WSEG; ++i) {
        const int c = cw[i];
        meta[b * NSEG + i] = r | (c << 16);
        cw[i] = r;
        r += c;
      }
      r = 0;
      for (int i = 0; i < TSEG; ++i) {
        const int c = ct[i];
        meta[b * NSEG + WSEG + i] = r | (c << 16);
        ct[i] = r;
        r += c;
      }
      r = 0;
      for (int i = 0; i < CSEG; ++i) {
        const int c = ccnt[i];
        meta[b * NSEG + WSEG + TSEG + i] = r | (c << 16);
        ccnt[i] = r;
        r += c;
      }
    }
    __syncthreads();

    int rw = 0, rt = 0, rc = 0;
    for (int s = 0; s < S_; ++s) {
      const int below = (s < t) ? 1 : 0;
      rw += below & (wid[s] == myw);
      rt += below & (tid_[s] == myt);
      rc += below & (cid[s] == myc);
    }
    lw[b * S_ + cw[myw] + rw] = t;
    lt[b * S_ + ct[myt] + rt] = t;
    lc[b * S_ + ccnt[myc] + rc] = t;
  } else if (blk < 448) {
    // ---- weight transpose/split: 3 z x 16 k-tiles x 8 n-tiles ----
    const int blk2 = blk - 64;
    const int z = blk2 >> 7;
    const int rem = blk2 & 127;
    const int k0 = (rem >> 3) * 64;
    const int n0 = (rem & 7) * 64;
    const float* W = (z == 0) ? Ws : ((z == 1) ? Wt_ : Wc);
    const int tx = t & 63, ty = (t >> 6) & 3;

    if (t < 256) {
#pragma unroll
      for (int i = 0; i < 16; ++i) {
        const int kl = i * 4 + ty;
        tile[kl][tx] = W[(size_t)(k0 + kl) * H_ + n0 + tx];
      }
    }
    __syncthreads();
    if (t < 256) {
      __bf16* oh = Wth + (size_t)z * H_ * D_;
      __bf16* ol = Wtl + (size_t)z * H_ * D_;
#pragma unroll
      for (int i = 0; i < 16; ++i) {
        const int nl = i * 4 + ty;
        const float v = tile[tx][nl];
        const __bf16 h = (__bf16)v;
        oh[(size_t)(n0 + nl) * D_ + k0 + tx] = h;
        ol[(size_t)(n0 + nl) * D_ + k0 + tx] = (__bf16)(v - (float)h);
      }
    }
  } else {
    // ---- ne fill: ent row 152 = no_entry, rows 153..159 zero ----
    const int b = blk - 448;
    const float v = ne[t];
    const __bf16 hi = (__bf16)v;
    const __bf16 lo = (__bf16)(v - (float)hi);
    ent_h[((size_t)b * EPAD + 152) * H_ + t] = hi;
    ent_l[((size_t)b * EPAD + 152) * H_ + t] = lo;
#pragma unroll
    for (int r = 153; r < EPAD; ++r) {
      ent_h[((size_t)b * EPAD + r) * H_ + t] = (__bf16)0.f;
      ent_l[((size_t)b * EPAD + r) * H_ + t] = (__bf16)0.f;
    }
  }
}

// ---------------------------------------------------------------------------
// Stage 1b: per-row gather-sum (R6-proven, ~60us, fabric-floor-bound).
// ---------------------------------------------------------------------------
__global__ __launch_bounds__(256) void gather_rows_kernel(
    const float* __restrict__ q, const int* __restrict__ lw,
    const int* __restrict__ lt, const int* __restrict__ lc,
    const int* __restrict__ meta, __bf16* __restrict__ Ah,
    __bf16* __restrict__ Al) {
  __shared__ int slist[S_];
  const int t = threadIdx.x;
  const int bid = blockIdx.x;
  const int r = (bid & 7) * (B_ * NSEG / 8) + (bid >> 3);
  const int b = r / NSEG;
  const int seg = r % NSEG;

  const int m = meta[r];
  const int start = m & 0xFFFF;
  const int count = m >> 16;

  const int* list;
  int arow;
  if (seg < WSEG) {
    list = lw;
    arow = b * WSEG + seg;
  } else if (seg < WSEG + TSEG) {
    list = lt;
    arow = B_ * WSEG + b * TSEG + (seg - WSEG);
  } else {
    list = lc;
    arow = B_ * (WSEG + TSEG) + b * CSEG + (seg - WSEG - TSEG);
  }

  for (int i = t; i < count; i += 256) slist[i] = list[b * S_ + start + i];
  __syncthreads();

  const float* qb = q + (size_t)b * S_ * D_;
  float4 acc = make_float4(0.f, 0.f, 0.f, 0.f);
  int i = 0;
  for (; i + 2 <= count; i += 2) {
    const float4 a = *(const float4*)(qb + (size_t)slist[i] * D_ + (t << 2));
    const float4 c =
        *(const float4*)(qb + (size_t)slist[i + 1] * D_ + (t << 2));
    acc.x += a.x + c.x;
    acc.y += a.y + c.y;
    acc.z += a.z + c.z;
    acc.w += a.w + c.w;
  }
  if (i < count) {
    const float4 a = *(const float4*)(qb + (size_t)slist[i] * D_ + (t << 2));
    acc.x += a.x;
    acc.y += a.y;
    acc.z += a.z;
    acc.w += a.w;
  }
  const __bf16 h0 = (__bf16)acc.x, h1 = (__bf16)acc.y, h2 = (__bf16)acc.z,
               h3 = (__bf16)acc.w;
  const bf16x4 hv = {h0, h1, h2, h3};
  const bf16x4 lv = {(__bf16)(acc.x - (float)h0), (__bf16)(acc.y - (float)h1),
                     (__bf16)(acc.z - (float)h2), (__bf16)(acc.w - (float)h3)};
  *(bf16x4*)(Ah + (size_t)arow * D_ + (t << 2)) = hv;
  *(bf16x4*)(Al + (size_t)arow * D_ + (t << 2)) = lv;
}

// ---------------------------------------------------------------------------
// Stage 2: split-bf16 MFMA GEMM, 128x128 tile, BK=64, XCD-swizzled grid.
// R11 change: 8 waves/block (512 thr), wave grid 2x4 (wave tile 64x32).
// Same 64KB LDS -> 2 blocks/CU x 8 waves = 16 waves/CU (4/SIMD, was 2/SIMD):
// doubles cross-wave overlap that hides the per-K-tile barrier drain.
// ---------------------------------------------------------------------------
__global__ __launch_bounds__(512) void gemm3_kernel(
    const __bf16* __restrict__ Ah, const __bf16* __restrict__ Al,
    const __bf16* __restrict__ Wth, const __bf16* __restrict__ Wtl,
    __bf16* __restrict__ sub_h, __bf16* __restrict__ sub_l,
    __bf16* __restrict__ ent_h, __bf16* __restrict__ ent_l) {
  __shared__ __align__(16) char smem[65536];
  char* sAh = smem;
  char* sAl = smem + 16384;
  char* sBh = smem + 32768;
  char* sBl = smem + 49152;

  const int tid = threadIdx.x;
  const int wid = tid >> 6;  // 0..7
  const int lane = tid & 63;
  // XCD swizzle: launched linear -> logical block (496 = 8 * 62, bijective)
  const int lin = blockIdx.x + blockIdx.y * 4;
  const int logical = (lin & 7) * 62 + (lin >> 3);
  const int m0 = (logical >> 2) * 128;
  const int n0 = (logical & 3) * 128;
  const int id = (m0 < B_ * WSEG) ? 0 : ((m0 < B_ * (WSEG + TSEG)) ? 1 : 2);

  const __bf16* Bh_g = Wth + (size_t)id * H_ * D_ + (size_t)n0 * D_;
  const __bf16* Bl_g = Wtl + (size_t)id * H_ * D_ + (size_t)n0 * D_;
  const __bf16* Ah_g = Ah + (size_t)m0 * D_;
  const __bf16* Al_g = Al + (size_t)m0 * D_;

  const int rsub = lane >> 3;
  const int csrc = (lane & 7) ^ rsub;

  const int wr = wid >> 2, wc = wid & 3;  // 2x4 wave grid
  const int arow0 = wr * 64 + (lane & 15);
  const int brow0 = wc * 32 + (lane & 15);
  const int cbase = (lane >> 4) * 16;
  const int sw = (lane & 7) << 4;

  f32x4 acc[4][2] = {};

#pragma unroll 1
  for (int kt = 0; kt < D_ / 64; ++kt) {
    __syncthreads();
    const size_t kofs = (size_t)kt * 64 + (size_t)csrc * 8;
#pragma unroll
    for (int j = 0; j < 2; ++j) {
      const int i = wid * 2 + j;  // 0..15
      const size_t grow = (size_t)(i * 8 + rsub) * D_ + kofs;
      GL16(Ah_g + grow, sAh + i * 1024);
      GL16(Al_g + grow, sAl + i * 1024);
      GL16(Bh_g + grow, sBh + i * 1024);
      GL16(Bl_g + grow, sBl + i * 1024);
    }
    __syncthreads();

#pragma unroll
    for (int ks = 0; ks < 2; ++ks) {
      const int cc = ((cbase + ks * 64) ^ sw);
      bf16x8 ah[4], al_[4], bh[2], bl_[2];
#pragma unroll
      for (int mi = 0; mi < 4; ++mi) {
        const int off = (arow0 + mi * 16) * 128 + cc;
        ah[mi] = *(const bf16x8*)(sAh + off);
        al_[mi] = *(const bf16x8*)(sAl + off);
      }
#pragma unroll
      for (int ni = 0; ni < 2; ++ni) {
        const int off = (brow0 + ni * 16) * 128 + cc;
        bh[ni] = *(const bf16x8*)(sBh + off);
        bl_[ni] = *(const bf16x8*)(sBl + off);
      }
#pragma unroll
      for (int mi = 0; mi < 4; ++mi)
#pragma unroll
        for (int ni = 0; ni < 2; ++ni) {
          acc[mi][ni] = __builtin_amdgcn_mfma_f32_16x16x32_bf16(
              ah[mi], bh[ni], acc[mi][ni], 0, 0, 0);
          acc[mi][ni] = __builtin_amdgcn_mfma_f32_16x16x32_bf16(
              ah[mi], bl_[ni], acc[mi][ni], 0, 0, 0);
          acc[mi][ni] = __builtin_amdgcn_mfma_f32_16x16x32_bf16(
              al_[mi], bh[ni], acc[mi][ni], 0, 0, 0);
        }
    }
  }

  const int rowb = m0 + wr * 64 + (lane >> 4) * 4;
  const int colb = n0 + wc * 32 + (lane & 15);
#pragma unroll
  for (int mi = 0; mi < 4; ++mi)
#pragma unroll
    for (int ni = 0; ni < 2; ++ni) {
      const f32x4 v = acc[mi][ni];
      const int col = colb + ni * 16;
#pragma unroll
      for (int r = 0; r < 4; ++r) {
        const int row = rowb + mi * 16 + r;
        const float val = tanh_fast(v[r]);
        const __bf16 h = (__bf16)val;
        const __bf16 l = (__bf16)(val - (float)h);
        size_t oix;
        __bf16 *oh, *ol;
        if (id == 0) {
          oix = (size_t)row * H_ + col;
          oh = sub_h;
          ol = sub_l;
        } else if (id == 1) {
          const int lr = row - B_ * WSEG;
          const int bb = lr / TSEG;
          const int rr = lr - bb * TSEG;
          oix = ((size_t)bb * EPAD + rr) * H_ + col;
          oh = ent_h;
          ol = ent_l;
        } else {
          const int lr = row - B_ * (WSEG + TSEG);
          const int bb = lr >> 7;
          const int rr = lr & 127;
          oix = ((size_t)bb * EPAD + TSEG + rr) * H_ + col;
          oh = ent_h;
          ol = ent_l;
        }
        oh[oix] = h;
        ol[oix] = l;
      }
    }
}

// ---------------------------------------------------------------------------
// Stage 3: att = softmax(sub @ ent^T) via split-bf16 MFMA.
// Grid = B*2 (2 blocks/batch, 48 rows each), 192 thr (3 waves).
// ---------------------------------------------------------------------------
__global__ __launch_bounds__(192) void attn_mfma_kernel(
    const __bf16* __restrict__ sub_h, const __bf16* __restrict__ sub_l,
    const __bf16* __restrict__ ent_h, const __bf16* __restrict__ ent_l,
    float* __restrict__ out) {
  __shared__ __align__(16) char smem[53248];
  char* sSh = smem;           // [48][64] bf16: 6 KB
  char* sSl = smem + 6144;    // 6 KB
  char* sEh = smem + 12288;   // [160][64] bf16: 20 KB
  char* sEl = smem + 32768;   // 20 KB

  const int tid = threadIdx.x;
  const int wid = tid >> 6;
  const int lane = tid & 63;
  const int b = blockIdx.x >> 1;
  const int half = blockIdx.x & 1;

  const __bf16* Sh_g = sub_h + ((size_t)b * WSEG + half * 48) * H_;
  const __bf16* Sl_g = sub_l + ((size_t)b * WSEG + half * 48) * H_;
  const __bf16* Eh_g = ent_h + (size_t)b * EPAD * H_;
  const __bf16* El_g = ent_l + (size_t)b * EPAD * H_;

  const int rsub = lane >> 3;
  const int csrc = (lane & 7) ^ rsub;

  const int arow0 = wid * 16 + (lane & 15);
  const int brow0 = lane & 15;
  const int cbase = (lane >> 4) * 16;
  const int sw = (lane & 7) << 4;

  f32x4 acc[10] = {};

#pragma unroll 1
  for (int kt = 0; kt < H_ / 64; ++kt) {
    __syncthreads();
    const size_t kofs = (size_t)kt * 64 + (size_t)csrc * 8;
#pragma unroll
    for (int j = 0; j < 18; ++j) {
      const int ig = wid * 18 + j;
      if (ig < 6) {
        GL16(Sh_g + (size_t)(ig * 8 + rsub) * H_ + kofs, sSh + ig * 1024);
      } else if (ig < 12) {
        const int i = ig - 6;
        GL16(Sl_g + (size_t)(i * 8 + rsub) * H_ + kofs, sSl + i * 1024);
      } else if (ig < 32) {
        const int i = ig - 12;
        GL16(Eh_g + (size_t)(i * 8 + rsub) * H_ + kofs, sEh + i * 1024);
      } else if (ig < 52) {
        const int i = ig - 32;
        GL16(El_g + (size_t)(i * 8 + rsub) * H_ + kofs, sEl + i * 1024);
      }
    }
    __syncthreads();

#pragma unroll
    for (int ks = 0; ks < 2; ++ks) {
      const int cc = ((cbase + ks * 64) ^ sw);
      const int aoff = arow0 * 128 + cc;
      const bf16x8 ah = *(const bf16x8*)(sSh + aoff);
      const bf16x8 al_ = *(const bf16x8*)(sSl + aoff);
#pragma unroll
      for (int ni = 0; ni < 10; ++ni) {
        const int off = (brow0 + ni * 16) * 128 + cc;
        const bf16x8 bh = *(const bf16x8*)(sEh + off);
        const bf16x8 bl_ = *(const bf16x8*)(sEl + off);
        acc[ni] = __builtin_amdgcn_mfma_f32_16x16x32_bf16(ah, bh, acc[ni], 0,
                                                          0, 0);
        acc[ni] = __builtin_amdgcn_mfma_f32_16x16x32_bf16(ah, bl_, acc[ni], 0,
                                                          0, 0);
        acc[ni] = __builtin_amdgcn_mfma_f32_16x16x32_bf16(al_, bh, acc[ni], 0,
                                                          0, 0);
      }
    }
  }

  __syncthreads();
  float (*lg)[EPAD] = (float(*)[EPAD])smem;  // 48*160*4 = 30720 B
  const int rowb = wid * 16 + (lane >> 4) * 4;
  const int colb = lane & 15;
#pragma unroll
  for (int ni = 0; ni < 10; ++ni) {
    const f32x4 v = acc[ni];
#pragma unroll
    for (int r = 0; r < 4; ++r) lg[rowb + r][colb + ni * 16] = v[r];
  }
  __syncthreads();

  for (int r = wid; r < 48; r += 3) {
    const float x0 = lg[r][lane];
    const float x1 = lg[r][lane + 64];
    const bool has2 = (lane + 128) < ESEG;
    const float x2 = has2 ? lg[r][lane + 128] : -INFINITY;
    float m = fmaxf(fmaxf(x0, x1), x2);
#pragma unroll
    for (int off = 32; off >= 1; off >>= 1) m = fmaxf(m, __shfl_xor(m, off, 64));
    const float p0 = expf(x0 - m);
    const float p1 = expf(x1 - m);
    const float p2 = has2 ? expf(x2 - m) : 0.f;
    float ssum = p0 + p1 + p2;
#pragma unroll
    for (int off = 32; off >= 1; off >>= 1) ssum += __shfl_xor(ssum, off, 64);
    const float inv = 1.f / ssum;
    float* ob = out + ((size_t)(b * WSEG + half * 48 + r)) * ESEG;
    ob[lane] = p0 * inv;
    ob[lane + 64] = p1 * inv;
    if (has2) ob[lane + 128] = p2 * inv;
  }
}

// ---------------------------------------------------------------------------
extern "C" void kernel_launch(void* const* d_in, const int* in_sizes, int n_in,
                              void* d_out, int out_size, void* d_ws,
                              size_t ws_size, hipStream_t stream) {
  const float* q = (const float*)d_in[0];
  const float* Wsub = (const float*)d_in[1];
  const float* Wtab = (const float*)d_in[2];
  const float* Wcol = (const float*)d_in[3];
  const float* ne = (const float*)d_in[4];
  const int* wseg = (const int*)d_in[5];
  const int* tseg = (const int*)d_in[6];
  const int* cseg = (const int*)d_in[7];
  float* out = (float*)d_out;

  // flat workspace layout (~105MB of the ~512MB ws)
  char* w = (char*)d_ws;
  __bf16* Ah = (__bf16*)(w);                 // 32,505,856
  __bf16* Al = (__bf16*)(w + 32505856);      // 32,505,856
  __bf16* ent_h = (__bf16*)(w + 65011712);   // 10,485,760
  __bf16* ent_l = (__bf16*)(w + 75497472);   // 10,485,760
  __bf16* Wth = (__bf16*)(w + 85983232);     //  3,145,728
  __bf16* Wtl = (__bf16*)(w + 89128960);     //  3,145,728
  __bf16* sub_h = (__bf16*)(w + 92274688);   //  6,291,456
  __bf16* sub_l = (__bf16*)(w + 98566144);   //  6,291,456
  int* lw = (int*)(w + 104857600);
  int* lt = (int*)(w + 104988672);
  int* lc = (int*)(w + 105119744);
  int* meta = (int*)(w + 105250816);

  setup_kernel<<<512, 512, 0, stream>>>(wseg, tseg, cseg, Wsub, Wtab, Wcol,
                                        ne, lw, lt, lc, meta, Wth, Wtl, ent_h,
                                        ent_l);
  gather_rows_kernel<<<B_ * NSEG, 256, 0, stream>>>(q, lw, lt, lc, meta, Ah,
                                                    Al);
  gemm3_kernel<<<dim3(4, 124), 512, 0, stream>>>(Ah, Al, Wth, Wtl, sub_h,
                                                 sub_l, ent_h, ent_l);
  attn_mfma_kernel<<<B_ * 2, 192, 0, stream>>>(sub_h, sub_l, ent_h, ent_l,
                                               out);
}

// Round 13
// 133.519 us; speedup vs baseline: 1.4768x; 1.0962x over previous
//
#include <hip/hip_runtime.h>
#include <hip/hip_bf16.h>
#include <math.h>

#define B_ 64
#define S_ 512
#define D_ 1024
#define H_ 512
#define WSEG 96
#define TSEG 24
#define CSEG 128
#define NSEG (WSEG + TSEG + CSEG) /* 248 */
#define ESEG (TSEG + CSEG + 1)    /* 153 */
#define EPAD 160                  /* ent rows padded per batch */

typedef __bf16 bf16x8 __attribute__((ext_vector_type(8)));
typedef __bf16 bf16x4 __attribute__((ext_vector_type(4)));
typedef _Float16 f16x8 __attribute__((ext_vector_type(8)));
typedef _Float16 f16x4 __attribute__((ext_vector_type(4)));
typedef float f32x4 __attribute__((ext_vector_type(4)));

#define GL16(g, l)                                                      \
  __builtin_amdgcn_global_load_lds(                                     \
      (const __attribute__((address_space(1))) void*)(g),               \
      (__attribute__((address_space(3))) void*)(l), 16, 0, 0)

__device__ inline float tanh_fast(float x) {
  const float xc = fminf(12.f, fmaxf(-12.f, x));
  const float e = __expf(2.f * xc);
  return (e - 1.f) * __builtin_amdgcn_rcpf(e + 1.f);
}

// ---------------------------------------------------------------------------
// Stage 1 (merged setup): blocks 0..63 = CSR build; 64..447 = weight
// transpose + fp16 hi/lo split; 448..511 = ne fill (bf16 hi/lo for attn).
// ---------------------------------------------------------------------------
__global__ __launch_bounds__(512) void setup_kernel(
    const int* __restrict__ wseg, const int* __restrict__ tseg,
    const int* __restrict__ cseg, const float* __restrict__ Ws,
    const float* __restrict__ Wt_, const float* __restrict__ Wc,
    const float* __restrict__ ne, int* __restrict__ lw, int* __restrict__ lt,
    int* __restrict__ lc, int* __restrict__ meta, _Float16* __restrict__ Wth,
    _Float16* __restrict__ Wtl, __bf16* __restrict__ ent_h,
    __bf16* __restrict__ ent_l) {
  __shared__ int wid[S_], tid_[S_], cid[S_];
  __shared__ int cw[WSEG], ct[TSEG], ccnt[CSEG];
  __shared__ float tile[64][65];
  const int blk = blockIdx.x;
  const int t = threadIdx.x;

  if (blk < 64) {
    // ---- CSR build, b = blk ----
    const int b = blk;
    const int myw = wseg[b * S_ + t];
    const int myt = tseg[b * S_ + t];
    const int myc = cseg[b * S_ + t];
    wid[t] = myw;
    tid_[t] = myt;
    cid[t] = myc;
    if (t < WSEG) cw[t] = 0;
    if (t < TSEG) ct[t] = 0;
    if (t < CSEG) ccnt[t] = 0;
    __syncthreads();

    atomicAdd(&cw[myw], 1);
    atomicAdd(&ct[myt], 1);
    atomicAdd(&ccnt[myc], 1);
    __syncthreads();

    if (t == 0) {
      int r = 0;
      for (int i = 0; i < WSEG; ++i) {
        const int c = cw[i];
        meta[b * NSEG + i] = r | (c << 16);
        cw[i] = r;
        r += c;
      }
      r = 0;
      for (int i = 0; i < TSEG; ++i) {
        const int c = ct[i];
        meta[b * NSEG + WSEG + i] = r | (c << 16);
        ct[i] = r;
        r += c;
      }
      r = 0;
      for (int i = 0; i < CSEG; ++i) {
        const int c = ccnt[i];
        meta[b * NSEG + WSEG + TSEG + i] = r | (c << 16);
        ccnt[i] = r;
        r += c;
      }
    }
    __syncthreads();

    int rw = 0, rt = 0, rc = 0;
    for (int s = 0; s < S_; ++s) {
      const int below = (s < t) ? 1 : 0;
      rw += below & (wid[s] == myw);
      rt += below & (tid_[s] == myt);
      rc += below & (cid[s] == myc);
    }
    lw[b * S_ + cw[myw] + rw] = t;
    lt[b * S_ + ct[myt] + rt] = t;
    lc[b * S_ + ccnt[myc] + rc] = t;
  } else if (blk < 448) {
    // ---- weight transpose + fp16 hi/lo split ----
    const int blk2 = blk - 64;
    const int z = blk2 >> 7;
    const int rem = blk2 & 127;
    const int k0 = (rem >> 3) * 64;
    const int n0 = (rem & 7) * 64;
    const float* W = (z == 0) ? Ws : ((z == 1) ? Wt_ : Wc);
    const int tx = t & 63, ty = (t >> 6) & 3;

    if (t < 256) {
#pragma unroll
      for (int i = 0; i < 16; ++i) {
        const int kl = i * 4 + ty;
        tile[kl][tx] = W[(size_t)(k0 + kl) * H_ + n0 + tx];
      }
    }
    __syncthreads();
    if (t < 256) {
      _Float16* oh = Wth + (size_t)z * H_ * D_;
      _Float16* ol = Wtl + (size_t)z * H_ * D_;
#pragma unroll
      for (int i = 0; i < 16; ++i) {
        const int nl = i * 4 + ty;
        const float v = tile[tx][nl];
        const _Float16 h = (_Float16)v;
        oh[(size_t)(n0 + nl) * D_ + k0 + tx] = h;
        ol[(size_t)(n0 + nl) * D_ + k0 + tx] = (_Float16)(v - (float)h);
      }
    }
  } else {
    // ---- ne fill (bf16 hi/lo, attn operands) ----
    const int b = blk - 448;
    const float v = ne[t];
    const __bf16 hi = (__bf16)v;
    const __bf16 lo = (__bf16)(v - (float)hi);
    ent_h[((size_t)b * EPAD + 152) * H_ + t] = hi;
    ent_l[((size_t)b * EPAD + 152) * H_ + t] = lo;
#pragma unroll
    for (int r = 153; r < EPAD; ++r) {
      ent_h[((size_t)b * EPAD + r) * H_ + t] = (__bf16)0.f;
      ent_l[((size_t)b * EPAD + r) * H_ + t] = (__bf16)0.f;
    }
  }
}

// ---------------------------------------------------------------------------
// Stage 1b: per-row gather-sum -> A fp16 (unsplit). R6-proven structure;
// writes halved vs hi/lo bf16 (32.5 MB total).
// ---------------------------------------------------------------------------
__global__ __launch_bounds__(256) void gather_rows_kernel(
    const float* __restrict__ q, const int* __restrict__ lw,
    const int* __restrict__ lt, const int* __restrict__ lc,
    const int* __restrict__ meta, _Float16* __restrict__ A) {
  __shared__ int slist[S_];
  const int t = threadIdx.x;
  const int bid = blockIdx.x;
  const int r = (bid & 7) * (B_ * NSEG / 8) + (bid >> 3);
  const int b = r / NSEG;
  const int seg = r % NSEG;

  const int m = meta[r];
  const int start = m & 0xFFFF;
  const int count = m >> 16;

  const int* list;
  int arow;
  if (seg < WSEG) {
    list = lw;
    arow = b * WSEG + seg;
  } else if (seg < WSEG + TSEG) {
    list = lt;
    arow = B_ * WSEG + b * TSEG + (seg - WSEG);
  } else {
    list = lc;
    arow = B_ * (WSEG + TSEG) + b * CSEG + (seg - WSEG - TSEG);
  }

  for (int i = t; i < count; i += 256) slist[i] = list[b * S_ + start + i];
  __syncthreads();

  const float* qb = q + (size_t)b * S_ * D_;
  float4 acc = make_float4(0.f, 0.f, 0.f, 0.f);
  int i = 0;
  for (; i + 2 <= count; i += 2) {
    const float4 a = *(const float4*)(qb + (size_t)slist[i] * D_ + (t << 2));
    const float4 c =
        *(const float4*)(qb + (size_t)slist[i + 1] * D_ + (t << 2));
    acc.x += a.x + c.x;
    acc.y += a.y + c.y;
    acc.z += a.z + c.z;
    acc.w += a.w + c.w;
  }
  if (i < count) {
    const float4 a = *(const float4*)(qb + (size_t)slist[i] * D_ + (t << 2));
    acc.x += a.x;
    acc.y += a.y;
    acc.z += a.z;
    acc.w += a.w;
  }
  const f16x4 hv = {(_Float16)acc.x, (_Float16)acc.y, (_Float16)acc.z,
                    (_Float16)acc.w};
  *(f16x4*)(A + (size_t)arow * D_ + (t << 2)) = hv;
}

// ---------------------------------------------------------------------------
// Stage 2: fp16 MFMA GEMM, 128x128 tile, BK=64, 2-PASS (a*wh + a*wl).
// 48 KB LDS (3 buffers). 4 waves, XCD-swizzled grid (R10-proven geometry).
// Epilogue still emits bf16 hi/lo sub/ent for the split-bf16 attn.
// ---------------------------------------------------------------------------
__global__ __launch_bounds__(256) void gemm3_kernel(
    const _Float16* __restrict__ A, const _Float16* __restrict__ Wth,
    const _Float16* __restrict__ Wtl, __bf16* __restrict__ sub_h,
    __bf16* __restrict__ sub_l, __bf16* __restrict__ ent_h,
    __bf16* __restrict__ ent_l) {
  __shared__ __align__(16) char smem[49152];
  char* sA = smem;            // [128][64] f16, swizzled: 16 KB
  char* sBh = smem + 16384;
  char* sBl = smem + 32768;

  const int tid = threadIdx.x;
  const int wid = tid >> 6;
  const int lane = tid & 63;
  // XCD swizzle: launched linear -> logical (496 = 8 * 62, bijective)
  const int lin = blockIdx.x + blockIdx.y * 4;
  const int logical = (lin & 7) * 62 + (lin >> 3);
  const int m0 = (logical >> 2) * 128;
  const int n0 = (logical & 3) * 128;
  const int id = (m0 < B_ * WSEG) ? 0 : ((m0 < B_ * (WSEG + TSEG)) ? 1 : 2);

  const _Float16* Bh_g = Wth + (size_t)id * H_ * D_ + (size_t)n0 * D_;
  const _Float16* Bl_g = Wtl + (size_t)id * H_ * D_ + (size_t)n0 * D_;
  const _Float16* A_g = A + (size_t)m0 * D_;

  const int rsub = lane >> 3;
  const int csrc = (lane & 7) ^ rsub;

  const int wr = wid >> 1, wc = wid & 1;
  const int arow0 = wr * 64 + (lane & 15);
  const int brow0 = wc * 64 + (lane & 15);
  const int cbase = (lane >> 4) * 16;
  const int sw = (lane & 7) << 4;

  f32x4 acc[4][4] = {};

#pragma unroll 1
  for (int kt = 0; kt < D_ / 64; ++kt) {
    __syncthreads();
    const size_t kofs = (size_t)kt * 64 + (size_t)csrc * 8;
#pragma unroll
    for (int j = 0; j < 4; ++j) {
      const int i = wid * 4 + j;
      const size_t grow = (size_t)(i * 8 + rsub) * D_ + kofs;
      GL16(A_g + grow, sA + i * 1024);
      GL16(Bh_g + grow, sBh + i * 1024);
      GL16(Bl_g + grow, sBl + i * 1024);
    }
    __syncthreads();

#pragma unroll
    for (int ks = 0; ks < 2; ++ks) {
      const int cc = ((cbase + ks * 64) ^ sw);
      f16x8 a[4], bh[4], bl_[4];
#pragma unroll
      for (int mi = 0; mi < 4; ++mi)
        a[mi] = *(const f16x8*)(sA + (arow0 + mi * 16) * 128 + cc);
#pragma unroll
      for (int ni = 0; ni < 4; ++ni) {
        const int off = (brow0 + ni * 16) * 128 + cc;
        bh[ni] = *(const f16x8*)(sBh + off);
        bl_[ni] = *(const f16x8*)(sBl + off);
      }
#pragma unroll
      for (int mi = 0; mi < 4; ++mi)
#pragma unroll
        for (int ni = 0; ni < 4; ++ni) {
          acc[mi][ni] = __builtin_amdgcn_mfma_f32_16x16x32_f16(
              a[mi], bh[ni], acc[mi][ni], 0, 0, 0);
          acc[mi][ni] = __builtin_amdgcn_mfma_f32_16x16x32_f16(
              a[mi], bl_[ni], acc[mi][ni], 0, 0, 0);
        }
    }
  }

  const int rowb = m0 + wr * 64 + (lane >> 4) * 4;
  const int colb = n0 + wc * 64 + (lane & 15);
#pragma unroll
  for (int mi = 0; mi < 4; ++mi)
#pragma unroll
    for (int ni = 0; ni < 4; ++ni) {
      const f32x4 v = acc[mi][ni];
      const int col = colb + ni * 16;
#pragma unroll
      for (int r = 0; r < 4; ++r) {
        const int row = rowb + mi * 16 + r;
        const float val = tanh_fast(v[r]);
        const __bf16 h = (__bf16)val;
        const __bf16 l = (__bf16)(val - (float)h);
        size_t oix;
        __bf16 *oh, *ol;
        if (id == 0) {
          oix = (size_t)row * H_ + col;
          oh = sub_h;
          ol = sub_l;
        } else if (id == 1) {
          const int lr = row - B_ * WSEG;
          const int bb = lr / TSEG;
          const int rr = lr - bb * TSEG;
          oix = ((size_t)bb * EPAD + rr) * H_ + col;
          oh = ent_h;
          ol = ent_l;
        } else {
          const int lr = row - B_ * (WSEG + TSEG);
          const int bb = lr >> 7;
          const int rr = lr & 127;
          oix = ((size_t)bb * EPAD + TSEG + rr) * H_ + col;
          oh = ent_h;
          ol = ent_l;
        }
        oh[oix] = h;
        ol[oix] = l;
      }
    }
}

// ---------------------------------------------------------------------------
// Stage 3: att = softmax(sub @ ent^T) via split-bf16 MFMA (unchanged).
// Grid = B*2 (2 blocks/batch, 48 rows each), 192 thr (3 waves).
// ---------------------------------------------------------------------------
__global__ __launch_bounds__(192) void attn_mfma_kernel(
    const __bf16* __restrict__ sub_h, const __bf16* __restrict__ sub_l,
    const __bf16* __restrict__ ent_h, const __bf16* __restrict__ ent_l,
    float* __restrict__ out) {
  __shared__ __align__(16) char smem[53248];
  char* sSh = smem;           // [48][64] bf16: 6 KB
  char* sSl = smem + 6144;    // 6 KB
  char* sEh = smem + 12288;   // [160][64] bf16: 20 KB
  char* sEl = smem + 32768;   // 20 KB

  const int tid = threadIdx.x;
  const int wid = tid >> 6;
  const int lane = tid & 63;
  const int b = blockIdx.x >> 1;
  const int half = blockIdx.x & 1;

  const __bf16* Sh_g = sub_h + ((size_t)b * WSEG + half * 48) * H_;
  const __bf16* Sl_g = sub_l + ((size_t)b * WSEG + half * 48) * H_;
  const __bf16* Eh_g = ent_h + (size_t)b * EPAD * H_;
  const __bf16* El_g = ent_l + (size_t)b * EPAD * H_;

  const int rsub = lane >> 3;
  const int csrc = (lane & 7) ^ rsub;

  const int arow0 = wid * 16 + (lane & 15);
  const int brow0 = lane & 15;
  const int cbase = (lane >> 4) * 16;
  const int sw = (lane & 7) << 4;

  f32x4 acc[10] = {};

#pragma unroll 1
  for (int kt = 0; kt < H_ / 64; ++kt) {
    __syncthreads();
    const size_t kofs = (size_t)kt * 64 + (size_t)csrc * 8;
#pragma unroll
    for (int j = 0; j < 18; ++j) {
      const int ig = wid * 18 + j;
      if (ig < 6) {
        GL16(Sh_g + (size_t)(ig * 8 + rsub) * H_ + kofs, sSh + ig * 1024);
      } else if (ig < 12) {
        const int i = ig - 6;
        GL16(Sl_g + (size_t)(i * 8 + rsub) * H_ + kofs, sSl + i * 1024);
      } else if (ig < 32) {
        const int i = ig - 12;
        GL16(Eh_g + (size_t)(i * 8 + rsub) * H_ + kofs, sEh + i * 1024);
      } else if (ig < 52) {
        const int i = ig - 32;
        GL16(El_g + (size_t)(i * 8 + rsub) * H_ + kofs, sEl + i * 1024);
      }
    }
    __syncthreads();

#pragma unroll
    for (int ks = 0; ks < 2; ++ks) {
      const int cc = ((cbase + ks * 64) ^ sw);
      const int aoff = arow0 * 128 + cc;
      const bf16x8 ah = *(const bf16x8*)(sSh + aoff);
      const bf16x8 al_ = *(const bf16x8*)(sSl + aoff);
#pragma unroll
      for (int ni = 0; ni < 10; ++ni) {
        const int off = (brow0 + ni * 16) * 128 + cc;
        const bf16x8 bh = *(const bf16x8*)(sEh + off);
        const bf16x8 bl_ = *(const bf16x8*)(sEl + off);
        acc[ni] = __builtin_amdgcn_mfma_f32_16x16x32_bf16(ah, bh, acc[ni], 0,
                                                          0, 0);
        acc[ni] = __builtin_amdgcn_mfma_f32_16x16x32_bf16(ah, bl_, acc[ni], 0,
                                                          0, 0);
        acc[ni] = __builtin_amdgcn_mfma_f32_16x16x32_bf16(al_, bh, acc[ni], 0,
                                                          0, 0);
      }
    }
  }

  __syncthreads();
  float (*lg)[EPAD] = (float(*)[EPAD])smem;  // 48*160*4 = 30720 B
  const int rowb = wid * 16 + (lane >> 4) * 4;
  const int colb = lane & 15;
#pragma unroll
  for (int ni = 0; ni < 10; ++ni) {
    const f32x4 v = acc[ni];
#pragma unroll
    for (int r = 0; r < 4; ++r) lg[rowb + r][colb + ni * 16] = v[r];
  }
  __syncthreads();

  for (int r = wid; r < 48; r += 3) {
    const float x0 = lg[r][lane];
    const float x1 = lg[r][lane + 64];
    const bool has2 = (lane + 128) < ESEG;
    const float x2 = has2 ? lg[r][lane + 128] : -INFINITY;
    float m = fmaxf(fmaxf(x0, x1), x2);
#pragma unroll
    for (int off = 32; off >= 1; off >>= 1) m = fmaxf(m, __shfl_xor(m, off, 64));
    const float p0 = expf(x0 - m);
    const float p1 = expf(x1 - m);
    const float p2 = has2 ? expf(x2 - m) : 0.f;
    float ssum = p0 + p1 + p2;
#pragma unroll
    for (int off = 32; off >= 1; off >>= 1) ssum += __shfl_xor(ssum, off, 64);
    const float inv = 1.f / ssum;
    float* ob = out + ((size_t)(b * WSEG + half * 48 + r)) * ESEG;
    ob[lane] = p0 * inv;
    ob[lane + 64] = p1 * inv;
    if (has2) ob[lane + 128] = p2 * inv;
  }
}

// ---------------------------------------------------------------------------
extern "C" void kernel_launch(void* const* d_in, const int* in_sizes, int n_in,
                              void* d_out, int out_size, void* d_ws,
                              size_t ws_size, hipStream_t stream) {
  const float* q = (const float*)d_in[0];
  const float* Wsub = (const float*)d_in[1];
  const float* Wtab = (const float*)d_in[2];
  const float* Wcol = (const float*)d_in[3];
  const float* ne = (const float*)d_in[4];
  const int* wseg = (const int*)d_in[5];
  const int* tseg = (const int*)d_in[6];
  const int* cseg = (const int*)d_in[7];
  float* out = (float*)d_out;

  // flat workspace layout (~73 MB of the ~512 MB ws)
  char* w = (char*)d_ws;
  _Float16* A = (_Float16*)(w);               // 32,505,856
  __bf16* ent_h = (__bf16*)(w + 32505856);    // 10,485,760
  __bf16* ent_l = (__bf16*)(w + 42991616);    // 10,485,760
  _Float16* Wth = (_Float16*)(w + 53477376);  //  3,145,728
  _Float16* Wtl = (_Float16*)(w + 56623104);  //  3,145,728
  __bf16* sub_h = (__bf16*)(w + 59768832);    //  6,291,456
  __bf16* sub_l = (__bf16*)(w + 66060288);    //  6,291,456
  int* lw = (int*)(w + 72351744);
  int* lt = (int*)(w + 72482816);
  int* lc = (int*)(w + 72613888);
  int* meta = (int*)(w + 72744960);

  setup_kernel<<<512, 512, 0, stream>>>(wseg, tseg, cseg, Wsub, Wtab, Wcol,
                                        ne, lw, lt, lc, meta, Wth, Wtl, ent_h,
                                        ent_l);
  gather_rows_kernel<<<B_ * NSEG, 256, 0, stream>>>(q, lw, lt, lc, meta, A);
  gemm3_kernel<<<dim3(4, 124), 256, 0, stream>>>(A, Wth, Wtl, sub_h, sub_l,
                                                 ent_h, ent_l);
  attn_mfma_kernel<<<B_ * 2, 192, 0, stream>>>(sub_h, sub_l, ent_h, ent_l,
                                               out);
}